// Round 3
// baseline (533.477 us; speedup 1.0000x reference)
//
#include <hip/hip_runtime.h>
#include <hip/hip_bf16.h>

#define N_NODES 50000
#define E_EDGES 600000
#define HDIM    128

#define QKV_BLOCKS  ((N_NODES + 31) / 32)     // 1563 (32 rows/block)
#define EDGE_BLOCKS ((E_EDGES + 255) / 256)   // 2344
#define SCAN_BLOCKS ((N_NODES + 255) / 256)   // 196
#define ROW_BLOCKS  (N_NODES / 4)             // 12500 (4 waves/block, 1 wave/row)

// ---- Phase 1: Q = x Wq^T + bq, K = x Wk^T + bk, V = x Wv^T + bv ----
// 32 rows/block. W tiles staged in LDS (coalesced fill, padded stride 36
// -> float4-aligned, conflict-free b128 reads). FMA-bound inner loop.
__global__ __launch_bounds__(256) void qkv_kernel(
    const float* __restrict__ x,
    const float* __restrict__ Wq, const float* __restrict__ bq,
    const float* __restrict__ Wk, const float* __restrict__ bk,
    const float* __restrict__ Wv, const float* __restrict__ bv,
    float* __restrict__ Q, float* __restrict__ K, float* __restrict__ V)
{
    __shared__ float xs[32][HDIM];          // 16 KB
    __shared__ float wtile[3][128][36];     // 54 KB (stride 36 floats = 144 B, 16B-aligned)
    const int r0 = blockIdx.x * 32;
    // stage x rows (clamp OOB to last row; stores are guarded)
    for (int i = threadIdx.x; i < 1024; i += 256) {
        const int r  = i >> 5;         // 32 float4 per row
        const int jj = i & 31;
        int gr = r0 + r; if (gr >= N_NODES) gr = N_NODES - 1;
        *(float4*)&xs[r][jj * 4] = *(const float4*)&x[(size_t)gr * HDIM + jj * 4];
    }
    const int c  = threadIdx.x & 127;
    const int rh = threadIdx.x >> 7;       // rows rh*16 .. rh*16+15
    float acc[3][16];
#pragma unroll
    for (int m = 0; m < 3; ++m)
#pragma unroll
        for (int i = 0; i < 16; ++i) acc[m][i] = 0.f;

    for (int ht = 0; ht < 4; ++ht) {
        __syncthreads();   // previous tile fully consumed (also covers xs fill)
        // stage 3 x [128][32] W tiles, coalesced 128B runs per row
        for (int i = threadIdx.x; i < 3 * 1024; i += 256) {
            const int mat = i >> 10;
            const int j   = i & 1023;
            const int cc  = j >> 3;
            const int hh  = j & 7;
            const float* Wsrc = (mat == 0) ? Wq : (mat == 1) ? Wk : Wv;
            float4 w = *(const float4*)&Wsrc[(size_t)cc * HDIM + ht * 32 + hh * 4];
            *(float4*)&wtile[mat][cc][hh * 4] = w;
        }
        __syncthreads();
#pragma unroll
        for (int g = 0; g < 8; ++g) {
            const float4 wq = *(const float4*)&wtile[0][c][g * 4];
            const float4 wk = *(const float4*)&wtile[1][c][g * 4];
            const float4 wv = *(const float4*)&wtile[2][c][g * 4];
#pragma unroll
            for (int i = 0; i < 16; ++i) {
                const float4 xv = *(const float4*)&xs[rh * 16 + i][ht * 32 + g * 4];
                acc[0][i] += xv.x * wq.x + xv.y * wq.y + xv.z * wq.z + xv.w * wq.w;
                acc[1][i] += xv.x * wk.x + xv.y * wk.y + xv.z * wk.z + xv.w * wk.w;
                acc[2][i] += xv.x * wv.x + xv.y * wv.y + xv.z * wv.z + xv.w * wv.w;
            }
        }
    }
    const float bqc = bq[c], bkc = bk[c], bvc = bv[c];
#pragma unroll
    for (int i = 0; i < 16; ++i) {
        const int gr = r0 + rh * 16 + i;
        if (gr < N_NODES) {
            const size_t base = (size_t)gr * HDIM + c;
            Q[base] = acc[0][i] + bqc;
            K[base] = acc[1][i] + bkc;
            V[base] = acc[2][i] + bvc;
        }
    }
}

// ---- Phase 2a: histogram of destination rows ----
__global__ __launch_bounds__(256) void hist_kernel(
    const int* __restrict__ ei, int* __restrict__ counts)
{
    const int e = blockIdx.x * 256 + threadIdx.x;
    if (e < E_EDGES) atomicAdd(&counts[ei[e]], 1);
}

// ---- Phase 2b: exclusive prefix scan (3 small kernels) ----
__global__ __launch_bounds__(256) void scan_partial_kernel(
    const int* __restrict__ counts, int* __restrict__ offs, int* __restrict__ aux)
{
    __shared__ int s[256];
    const int i = blockIdx.x * 256 + threadIdx.x;
    const int v = (i < N_NODES) ? counts[i] : 0;
    s[threadIdx.x] = v;
    __syncthreads();
    for (int d = 1; d < 256; d <<= 1) {
        int t = (threadIdx.x >= d) ? s[threadIdx.x - d] : 0;
        __syncthreads();
        s[threadIdx.x] += t;
        __syncthreads();
    }
    if (i < N_NODES) offs[i] = s[threadIdx.x] - v;   // exclusive within block
    if (threadIdx.x == 255) aux[blockIdx.x] = s[255];
}

__global__ __launch_bounds__(256) void scan_aux_kernel(int* __restrict__ aux)
{
    __shared__ int s[256];
    const int i = threadIdx.x;
    const int v = (i < SCAN_BLOCKS) ? aux[i] : 0;
    s[i] = v;
    __syncthreads();
    for (int d = 1; d < 256; d <<= 1) {
        int t = (i >= d) ? s[i - d] : 0;
        __syncthreads();
        s[i] += t;
        __syncthreads();
    }
    if (i < SCAN_BLOCKS) aux[i] = s[i] - v;          // exclusive
}

__global__ __launch_bounds__(256) void scan_add_kernel(
    int* __restrict__ offs, const int* __restrict__ aux, int* __restrict__ cursor)
{
    const int i = blockIdx.x * 256 + threadIdx.x;
    if (i < N_NODES) {
        const int o = offs[i] + aux[blockIdx.x];
        offs[i] = o;
        cursor[i] = o;
    }
}

// ---- Phase 2c: bin edges by destination row ----
__global__ __launch_bounds__(256) void bin_kernel(
    const int* __restrict__ ei, const float* __restrict__ ew,
    int* __restrict__ cursor, int* __restrict__ bcol, float* __restrict__ bew)
{
    const int e = blockIdx.x * 256 + threadIdx.x;
    if (e >= E_EDGES) return;
    const int row = ei[e];
    const int pos = atomicAdd(&cursor[row], 1);
    bcol[pos] = ei[E_EDGES + e];
    bew[pos]  = ew[e];
}

// ---- Phase 3: per-edge energy (one wave per row, Q row cached in regs) ----
__global__ __launch_bounds__(256) void energy_kernel(
    const float* __restrict__ Q, const float* __restrict__ K,
    const int* __restrict__ offs, const int* __restrict__ counts,
    const int* __restrict__ bcol, const float* __restrict__ bew,
    float* __restrict__ bp, float* __restrict__ blockmax)
{
    const int row  = (blockIdx.x * 256 + threadIdx.x) >> 6;
    const int lane = threadIdx.x & 63;
    const int start = offs[row], len = counts[row];
    const float2 q = *(const float2*)&Q[(size_t)row * HDIM + lane * 2];
    const float inv_scale = 0.08838834764831845f;  // 1/sqrt(128)
    float lmax = -3.4e38f;
    for (int j = 0; j < len; ++j) {
        const int   c = bcol[start + j];
        const float w = bew[start + j];
        float2 k = *(const float2*)&K[(size_t)c * HDIM + lane * 2];
        float d = q.x * k.x + q.y * k.y;
#pragma unroll
        for (int m = 32; m >= 1; m >>= 1) d += __shfl_xor(d, m);
        const float en = d * inv_scale * w;
        if (lane == 0) bp[start + j] = en;
        lmax = fmaxf(lmax, en);
    }
    __shared__ float sm[4];
    if (lane == 0) sm[threadIdx.x >> 6] = lmax;
    __syncthreads();
    if (threadIdx.x == 0)
        blockmax[blockIdx.x] = fmaxf(fmaxf(sm[0], sm[1]), fmaxf(sm[2], sm[3]));
}

__global__ __launch_bounds__(256) void reduce_max_kernel(
    const float* __restrict__ bm, int n, float* __restrict__ gmax)
{
    float m = -3.4e38f;
    for (int i = threadIdx.x; i < n; i += 256) m = fmaxf(m, bm[i]);
#pragma unroll
    for (int s = 32; s >= 1; s >>= 1) m = fmaxf(m, __shfl_xor(m, s));
    __shared__ float sm[4];
    if ((threadIdx.x & 63) == 0) sm[threadIdx.x >> 6] = m;
    __syncthreads();
    if (threadIdx.x == 0) *gmax = fmaxf(fmaxf(sm[0], sm[1]), fmaxf(sm[2], sm[3]));
}

// ---- Phase 4: p = exp(en - max), partial sums ----
__global__ __launch_bounds__(256) void expsum_kernel(
    float* __restrict__ bp, const float* __restrict__ gmax,
    float* __restrict__ blocksum)
{
    const float m = *gmax;
    const int e = blockIdx.x * 256 + threadIdx.x;
    float p = 0.f;
    if (e < E_EDGES) { p = __expf(bp[e] - m); bp[e] = p; }
#pragma unroll
    for (int s = 32; s >= 1; s >>= 1) p += __shfl_xor(p, s);
    __shared__ float sm[4];
    if ((threadIdx.x & 63) == 0) sm[threadIdx.x >> 6] = p;
    __syncthreads();
    if (threadIdx.x == 0) blocksum[blockIdx.x] = sm[0] + sm[1] + sm[2] + sm[3];
}

__global__ __launch_bounds__(256) void reduce_sum_kernel(
    const float* __restrict__ bs, int n, float* __restrict__ gsum)
{
    float v = 0.f;
    for (int i = threadIdx.x; i < n; i += 256) v += bs[i];
#pragma unroll
    for (int s = 32; s >= 1; s >>= 1) v += __shfl_xor(v, s);
    __shared__ float sm[4];
    if ((threadIdx.x & 63) == 0) sm[threadIdx.x >> 6] = v;
    __syncthreads();
    if (threadIdx.x == 0) *gsum = sm[0] + sm[1] + sm[2] + sm[3];
}

// ---- Phase 5: out[row] = sum_j V[bcol[j]] * p[j] / gsum  (no atomics) ----
__global__ __launch_bounds__(256) void accum_kernel(
    const float* __restrict__ V,
    const int* __restrict__ offs, const int* __restrict__ counts,
    const int* __restrict__ bcol, const float* __restrict__ bp,
    const float* __restrict__ gsum, float* __restrict__ out)
{
    const int row  = (blockIdx.x * 256 + threadIdx.x) >> 6;
    const int lane = threadIdx.x & 63;
    const float inv = 1.0f / *gsum;
    const int start = offs[row], len = counts[row];
    float ax = 0.f, ay = 0.f;
    for (int j = 0; j < len; ++j) {
        const int   c = bcol[start + j];
        const float w = bp[start + j] * inv;
        float2 v = *(const float2*)&V[(size_t)c * HDIM + lane * 2];
        ax += v.x * w;
        ay += v.y * w;
    }
    *(float2*)&out[(size_t)row * HDIM + lane * 2] = make_float2(ax, ay);
}

extern "C" void kernel_launch(void* const* d_in, const int* in_sizes, int n_in,
                              void* d_out, int out_size, void* d_ws, size_t ws_size,
                              hipStream_t stream)
{
    const float* x  = (const float*)d_in[0];
    const int*   ei = (const int*)d_in[1];
    const float* ew = (const float*)d_in[2];
    const float* Wq = (const float*)d_in[3];
    const float* bq = (const float*)d_in[4];
    const float* Wk = (const float*)d_in[5];
    const float* bk = (const float*)d_in[6];
    const float* Wv = (const float*)d_in[7];
    const float* bv = (const float*)d_in[8];
    float* out = (float*)d_out;

    float* ws = (float*)d_ws;
    float* Q       = ws;                                  // N*H
    float* K       = Q + (size_t)N_NODES * HDIM;          // N*H
    float* V       = K + (size_t)N_NODES * HDIM;          // N*H
    float* fp      = V + (size_t)N_NODES * HDIM;
    int*   counts  = (int*)fp;                            // N
    int*   offs    = counts + N_NODES;                    // N
    int*   cursor  = offs + N_NODES;                      // N
    int*   aux     = cursor + N_NODES;                    // SCAN_BLOCKS
    int*   bcol    = aux + 256;                           // E
    float* bew     = (float*)(bcol + E_EDGES);            // E
    float* bp      = bew + E_EDGES;                       // E
    float* blockmax= bp + E_EDGES;                        // ROW_BLOCKS
    float* blocksum= blockmax + ROW_BLOCKS;               // EDGE_BLOCKS
    float* gmax    = blocksum + EDGE_BLOCKS;              // 1
    float* gsum    = gmax + 1;                            // 1

    hipMemsetAsync(counts, 0, N_NODES * sizeof(int), stream);

    qkv_kernel<<<QKV_BLOCKS, 256, 0, stream>>>(x, Wq, bq, Wk, bk, Wv, bv, Q, K, V);
    hist_kernel<<<EDGE_BLOCKS, 256, 0, stream>>>(ei, counts);
    scan_partial_kernel<<<SCAN_BLOCKS, 256, 0, stream>>>(counts, offs, aux);
    scan_aux_kernel<<<1, 256, 0, stream>>>(aux);
    scan_add_kernel<<<SCAN_BLOCKS, 256, 0, stream>>>(offs, aux, cursor);
    bin_kernel<<<EDGE_BLOCKS, 256, 0, stream>>>(ei, ew, cursor, bcol, bew);
    energy_kernel<<<ROW_BLOCKS, 256, 0, stream>>>(Q, K, offs, counts, bcol, bew, bp, blockmax);
    reduce_max_kernel<<<1, 256, 0, stream>>>(blockmax, ROW_BLOCKS, gmax);
    expsum_kernel<<<EDGE_BLOCKS, 256, 0, stream>>>(bp, gmax, blocksum);
    reduce_sum_kernel<<<1, 256, 0, stream>>>(blocksum, EDGE_BLOCKS, gsum);
    accum_kernel<<<ROW_BLOCKS, 256, 0, stream>>>(V, offs, counts, bcol, bp, gsum, out);
}

// Round 4
// 446.984 us; speedup vs baseline: 1.1935x; 1.1935x over previous
//
#include <hip/hip_runtime.h>
#include <hip/hip_bf16.h>

#define N_NODES 50000
#define E_EDGES 600000
#define HDIM    128

#define QKV_BLOCKS  ((N_NODES + 31) / 32)     // 1563 (32 rows/block)
#define EDGE_BLOCKS ((E_EDGES + 255) / 256)   // 2344
#define SCAN_BLOCKS ((N_NODES + 255) / 256)   // 196
#define ROW_BLOCKS  (N_NODES / 4)             // 12500 (4 waves/block, 1 wave/row)

// ---- Phase 0: WT[h][c] = W[c][h] for the three weight matrices ----
__global__ __launch_bounds__(256) void transpose_w_kernel(
    const float* __restrict__ Wq, const float* __restrict__ Wk,
    const float* __restrict__ Wv,
    float* __restrict__ WTq, float* __restrict__ WTk, float* __restrict__ WTv)
{
    __shared__ float t[32][33];
    const int mat  = blockIdx.x >> 4;       // 0..2
    const int tile = blockIdx.x & 15;       // 4x4 grid of 32x32 tiles
    const int tr = (tile >> 2) * 32;        // c offset
    const int tc = (tile & 3) * 32;         // h offset
    const float* W  = (mat == 0) ? Wq  : (mat == 1) ? Wk  : Wv;
    float*       WT = (mat == 0) ? WTq : (mat == 1) ? WTk : WTv;
    const int lr = threadIdx.x >> 5;        // 0..7
    const int lc = threadIdx.x & 31;
#pragma unroll
    for (int i = 0; i < 4; ++i) {
        const int r = lr + i * 8;
        t[r][lc] = W[(size_t)(tr + r) * HDIM + tc + lc];
    }
    __syncthreads();
#pragma unroll
    for (int i = 0; i < 4; ++i) {
        const int r = lr + i * 8;
        WT[(size_t)(tc + r) * HDIM + tr + lc] = t[lc][r];
    }
}

// ---- Phase 1: Q = x Wq^T + bq, K = x Wk^T + bk, V = x Wv^T + bv ----
// Thread (cq,rg): cols 4cq..4cq+3 (coalesced b128 WT loads), rows 4rg..4rg+3.
// 48 VGPR of accumulators; xs broadcast reads are 2-address (free).
__global__ __launch_bounds__(256) void qkv_kernel(
    const float* __restrict__ x,
    const float* __restrict__ WTq, const float* __restrict__ bq,
    const float* __restrict__ WTk, const float* __restrict__ bk,
    const float* __restrict__ WTv, const float* __restrict__ bv,
    float* __restrict__ Q, float* __restrict__ K, float* __restrict__ V)
{
    __shared__ float xs[32][HDIM];          // 16 KB
    const int r0 = blockIdx.x * 32;
    for (int i = threadIdx.x; i < 32 * HDIM / 4; i += 256) {
        const int r = i >> 5, jj = i & 31;
        int gr = r0 + r; if (gr >= N_NODES) gr = N_NODES - 1;
        *(float4*)&xs[r][jj * 4] = *(const float4*)&x[(size_t)gr * HDIM + jj * 4];
    }
    __syncthreads();
    const int cq = threadIdx.x & 31;        // column group
    const int rg = threadIdx.x >> 5;        // row group
    float4 aq[4], ak[4], av[4];
#pragma unroll
    for (int i = 0; i < 4; ++i) {
        aq[i] = make_float4(0.f, 0.f, 0.f, 0.f);
        ak[i] = make_float4(0.f, 0.f, 0.f, 0.f);
        av[i] = make_float4(0.f, 0.f, 0.f, 0.f);
    }
#pragma unroll 4
    for (int h = 0; h < HDIM; ++h) {
        const float4 wq = *(const float4*)&WTq[(size_t)h * HDIM + cq * 4];
        const float4 wk = *(const float4*)&WTk[(size_t)h * HDIM + cq * 4];
        const float4 wv = *(const float4*)&WTv[(size_t)h * HDIM + cq * 4];
#pragma unroll
        for (int i = 0; i < 4; ++i) {
            const float xv = xs[rg * 4 + i][h];
            aq[i].x += wq.x * xv; aq[i].y += wq.y * xv;
            aq[i].z += wq.z * xv; aq[i].w += wq.w * xv;
            ak[i].x += wk.x * xv; ak[i].y += wk.y * xv;
            ak[i].z += wk.z * xv; ak[i].w += wk.w * xv;
            av[i].x += wv.x * xv; av[i].y += wv.y * xv;
            av[i].z += wv.z * xv; av[i].w += wv.w * xv;
        }
    }
    const float4 b_q = *(const float4*)&bq[cq * 4];
    const float4 b_k = *(const float4*)&bk[cq * 4];
    const float4 b_v = *(const float4*)&bv[cq * 4];
#pragma unroll
    for (int i = 0; i < 4; ++i) {
        const int gr = r0 + rg * 4 + i;
        if (gr < N_NODES) {
            const size_t base = (size_t)gr * HDIM + cq * 4;
            *(float4*)&Q[base] = make_float4(aq[i].x + b_q.x, aq[i].y + b_q.y,
                                             aq[i].z + b_q.z, aq[i].w + b_q.w);
            *(float4*)&K[base] = make_float4(ak[i].x + b_k.x, ak[i].y + b_k.y,
                                             ak[i].z + b_k.z, ak[i].w + b_k.w);
            *(float4*)&V[base] = make_float4(av[i].x + b_v.x, av[i].y + b_v.y,
                                             av[i].z + b_v.z, av[i].w + b_v.w);
        }
    }
}

// ---- Phase 2a: histogram of destination rows ----
__global__ __launch_bounds__(256) void hist_kernel(
    const int* __restrict__ ei, int* __restrict__ counts)
{
    const int e = blockIdx.x * 256 + threadIdx.x;
    if (e < E_EDGES) atomicAdd(&counts[ei[e]], 1);
}

// ---- Phase 2b: exclusive prefix scan (3 small kernels) ----
__global__ __launch_bounds__(256) void scan_partial_kernel(
    const int* __restrict__ counts, int* __restrict__ offs, int* __restrict__ aux)
{
    __shared__ int s[256];
    const int i = blockIdx.x * 256 + threadIdx.x;
    const int v = (i < N_NODES) ? counts[i] : 0;
    s[threadIdx.x] = v;
    __syncthreads();
    for (int d = 1; d < 256; d <<= 1) {
        int t = (threadIdx.x >= d) ? s[threadIdx.x - d] : 0;
        __syncthreads();
        s[threadIdx.x] += t;
        __syncthreads();
    }
    if (i < N_NODES) offs[i] = s[threadIdx.x] - v;   // exclusive within block
    if (threadIdx.x == 255) aux[blockIdx.x] = s[255];
}

__global__ __launch_bounds__(256) void scan_aux_kernel(int* __restrict__ aux)
{
    __shared__ int s[256];
    const int i = threadIdx.x;
    const int v = (i < SCAN_BLOCKS) ? aux[i] : 0;
    s[i] = v;
    __syncthreads();
    for (int d = 1; d < 256; d <<= 1) {
        int t = (i >= d) ? s[i - d] : 0;
        __syncthreads();
        s[i] += t;
        __syncthreads();
    }
    if (i < SCAN_BLOCKS) aux[i] = s[i] - v;          // exclusive
}

__global__ __launch_bounds__(256) void scan_add_kernel(
    int* __restrict__ offs, const int* __restrict__ aux, int* __restrict__ cursor)
{
    const int i = blockIdx.x * 256 + threadIdx.x;
    if (i < N_NODES) {
        const int o = offs[i] + aux[blockIdx.x];
        offs[i] = o;
        cursor[i] = o;
    }
}

// ---- Phase 2c: bin edges by destination row ----
__global__ __launch_bounds__(256) void bin_kernel(
    const int* __restrict__ ei, const float* __restrict__ ew,
    int* __restrict__ cursor, int* __restrict__ bcol, float* __restrict__ bew)
{
    const int e = blockIdx.x * 256 + threadIdx.x;
    if (e >= E_EDGES) return;
    const int row = ei[e];
    const int pos = atomicAdd(&cursor[row], 1);
    bcol[pos] = ei[E_EDGES + e];
    bew[pos]  = ew[e];
}

// ---- Phase 3: per-edge energy (one wave per row, Q row cached in regs) ----
__global__ __launch_bounds__(256) void energy_kernel(
    const float* __restrict__ Q, const float* __restrict__ K,
    const int* __restrict__ offs, const int* __restrict__ counts,
    const int* __restrict__ bcol, const float* __restrict__ bew,
    float* __restrict__ bp, float* __restrict__ blockmax)
{
    const int row  = (blockIdx.x * 256 + threadIdx.x) >> 6;
    const int lane = threadIdx.x & 63;
    const int start = offs[row], len = counts[row];
    const float2 q = *(const float2*)&Q[(size_t)row * HDIM + lane * 2];
    const float inv_scale = 0.08838834764831845f;  // 1/sqrt(128)
    float lmax = -3.4e38f;
    for (int j = 0; j < len; ++j) {
        const int   c = bcol[start + j];
        const float w = bew[start + j];
        float2 k = *(const float2*)&K[(size_t)c * HDIM + lane * 2];
        float d = q.x * k.x + q.y * k.y;
#pragma unroll
        for (int m = 32; m >= 1; m >>= 1) d += __shfl_xor(d, m);
        const float en = d * inv_scale * w;
        if (lane == 0) bp[start + j] = en;
        lmax = fmaxf(lmax, en);
    }
    __shared__ float sm[4];
    if (lane == 0) sm[threadIdx.x >> 6] = lmax;
    __syncthreads();
    if (threadIdx.x == 0)
        blockmax[blockIdx.x] = fmaxf(fmaxf(sm[0], sm[1]), fmaxf(sm[2], sm[3]));
}

__global__ __launch_bounds__(256) void reduce_max_kernel(
    const float* __restrict__ bm, int n, float* __restrict__ gmax)
{
    float m = -3.4e38f;
    for (int i = threadIdx.x; i < n; i += 256) m = fmaxf(m, bm[i]);
#pragma unroll
    for (int s = 32; s >= 1; s >>= 1) m = fmaxf(m, __shfl_xor(m, s));
    __shared__ float sm[4];
    if ((threadIdx.x & 63) == 0) sm[threadIdx.x >> 6] = m;
    __syncthreads();
    if (threadIdx.x == 0) *gmax = fmaxf(fmaxf(sm[0], sm[1]), fmaxf(sm[2], sm[3]));
}

// ---- Phase 4: p = exp(en - max), partial sums ----
__global__ __launch_bounds__(256) void expsum_kernel(
    float* __restrict__ bp, const float* __restrict__ gmax,
    float* __restrict__ blocksum)
{
    const float m = *gmax;
    const int e = blockIdx.x * 256 + threadIdx.x;
    float p = 0.f;
    if (e < E_EDGES) { p = __expf(bp[e] - m); bp[e] = p; }
#pragma unroll
    for (int s = 32; s >= 1; s >>= 1) p += __shfl_xor(p, s);
    __shared__ float sm[4];
    if ((threadIdx.x & 63) == 0) sm[threadIdx.x >> 6] = p;
    __syncthreads();
    if (threadIdx.x == 0) blocksum[blockIdx.x] = sm[0] + sm[1] + sm[2] + sm[3];
}

__global__ __launch_bounds__(256) void reduce_sum_kernel(
    const float* __restrict__ bs, int n, float* __restrict__ gsum)
{
    float v = 0.f;
    for (int i = threadIdx.x; i < n; i += 256) v += bs[i];
#pragma unroll
    for (int s = 32; s >= 1; s >>= 1) v += __shfl_xor(v, s);
    __shared__ float sm[4];
    if ((threadIdx.x & 63) == 0) sm[threadIdx.x >> 6] = v;
    __syncthreads();
    if (threadIdx.x == 0) *gsum = sm[0] + sm[1] + sm[2] + sm[3];
}

// ---- Phase 5: out[row] = sum_j V[bcol[j]] * p[j] / gsum  (no atomics) ----
__global__ __launch_bounds__(256) void accum_kernel(
    const float* __restrict__ V,
    const int* __restrict__ offs, const int* __restrict__ counts,
    const int* __restrict__ bcol, const float* __restrict__ bp,
    const float* __restrict__ gsum, float* __restrict__ out)
{
    const int row  = (blockIdx.x * 256 + threadIdx.x) >> 6;
    const int lane = threadIdx.x & 63;
    const float inv = 1.0f / *gsum;
    const int start = offs[row], len = counts[row];
    float ax = 0.f, ay = 0.f;
    for (int j = 0; j < len; ++j) {
        const int   c = bcol[start + j];
        const float w = bp[start + j] * inv;
        float2 v = *(const float2*)&V[(size_t)c * HDIM + lane * 2];
        ax += v.x * w;
        ay += v.y * w;
    }
    *(float2*)&out[(size_t)row * HDIM + lane * 2] = make_float2(ax, ay);
}

extern "C" void kernel_launch(void* const* d_in, const int* in_sizes, int n_in,
                              void* d_out, int out_size, void* d_ws, size_t ws_size,
                              hipStream_t stream)
{
    const float* x  = (const float*)d_in[0];
    const int*   ei = (const int*)d_in[1];
    const float* ew = (const float*)d_in[2];
    const float* Wq = (const float*)d_in[3];
    const float* bq = (const float*)d_in[4];
    const float* Wk = (const float*)d_in[5];
    const float* bk = (const float*)d_in[6];
    const float* Wv = (const float*)d_in[7];
    const float* bv = (const float*)d_in[8];
    float* out = (float*)d_out;

    float* ws = (float*)d_ws;
    float* Q       = ws;                                  // N*H
    float* K       = Q + (size_t)N_NODES * HDIM;          // N*H
    float* V       = K + (size_t)N_NODES * HDIM;          // N*H
    float* fp      = V + (size_t)N_NODES * HDIM;
    int*   counts  = (int*)fp;                            // N
    int*   offs    = counts + N_NODES;                    // N
    int*   cursor  = offs + N_NODES;                      // N
    int*   aux     = cursor + N_NODES;                    // SCAN_BLOCKS
    int*   bcol    = aux + 256;                           // E
    float* bew     = (float*)(bcol + E_EDGES);            // E
    float* bp      = bew + E_EDGES;                       // E
    float* blockmax= bp + E_EDGES;                        // ROW_BLOCKS
    float* blocksum= blockmax + ROW_BLOCKS;               // EDGE_BLOCKS
    float* gmax    = blocksum + EDGE_BLOCKS;              // 1
    float* gsum    = gmax + 1;                            // 1
    float* WTq     = gsum + 1;                            // 128*128
    float* WTk     = WTq + HDIM * HDIM;                   // 128*128
    float* WTv     = WTk + HDIM * HDIM;                   // 128*128

    hipMemsetAsync(counts, 0, N_NODES * sizeof(int), stream);

    transpose_w_kernel<<<48, 256, 0, stream>>>(Wq, Wk, Wv, WTq, WTk, WTv);
    qkv_kernel<<<QKV_BLOCKS, 256, 0, stream>>>(x, WTq, bq, WTk, bk, WTv, bv, Q, K, V);
    hist_kernel<<<EDGE_BLOCKS, 256, 0, stream>>>(ei, counts);
    scan_partial_kernel<<<SCAN_BLOCKS, 256, 0, stream>>>(counts, offs, aux);
    scan_aux_kernel<<<1, 256, 0, stream>>>(aux);
    scan_add_kernel<<<SCAN_BLOCKS, 256, 0, stream>>>(offs, aux, cursor);
    bin_kernel<<<EDGE_BLOCKS, 256, 0, stream>>>(ei, ew, cursor, bcol, bew);
    energy_kernel<<<ROW_BLOCKS, 256, 0, stream>>>(Q, K, offs, counts, bcol, bew, bp, blockmax);
    reduce_max_kernel<<<1, 256, 0, stream>>>(blockmax, ROW_BLOCKS, gmax);
    expsum_kernel<<<EDGE_BLOCKS, 256, 0, stream>>>(bp, gmax, blocksum);
    reduce_sum_kernel<<<1, 256, 0, stream>>>(blocksum, EDGE_BLOCKS, gsum);
    accum_kernel<<<ROW_BLOCKS, 256, 0, stream>>>(V, offs, counts, bcol, bp, gsum, out);
}

// Round 5
// 342.413 us; speedup vs baseline: 1.5580x; 1.3054x over previous
//
#include <hip/hip_runtime.h>
#include <hip/hip_bf16.h>

#define N_NODES 50000
#define E_EDGES 600000
#define HDIM    128

#define QKV_BLOCKS  ((N_NODES + 31) / 32)     // 1563 (32 rows/block, 128 thr)
#define EDGE_BLOCKS ((E_EDGES + 255) / 256)   // 2344
#define SCAN_BLOCKS ((N_NODES + 255) / 256)   // 196
#define ROW_BLOCKS  (N_NODES / 4)             // 12500 (4 waves/block, 1 wave/row)

// ---- Phase 0: WT[h][c] = W[c][h] for the three weight matrices ----
__global__ __launch_bounds__(256) void transpose_w_kernel(
    const float* __restrict__ Wq, const float* __restrict__ Wk,
    const float* __restrict__ Wv,
    float* __restrict__ WTq, float* __restrict__ WTk, float* __restrict__ WTv)
{
    __shared__ float t[32][33];
    const int mat  = blockIdx.x >> 4;       // 0..2
    const int tile = blockIdx.x & 15;       // 4x4 grid of 32x32 tiles
    const int tr = (tile >> 2) * 32;        // c offset
    const int tc = (tile & 3) * 32;         // h offset
    const float* W  = (mat == 0) ? Wq  : (mat == 1) ? Wk  : Wv;
    float*       WT = (mat == 0) ? WTq : (mat == 1) ? WTk : WTv;
    const int lr = threadIdx.x >> 5;        // 0..7
    const int lc = threadIdx.x & 31;
#pragma unroll
    for (int i = 0; i < 4; ++i) {
        const int r = lr + i * 8;
        t[r][lc] = W[(size_t)(tr + r) * HDIM + tc + lc];
    }
    __syncthreads();
#pragma unroll
    for (int i = 0; i < 4; ++i) {
        const int r = lr + i * 8;
        WT[(size_t)(tc + r) * HDIM + tr + lc] = t[lc][r];
    }
}

// ---- Phase 1: Q = x Wq^T + bq, K = x Wk^T + bk, V = x Wv^T + bv ----
// 128 threads, 32 rows/block, 8 rows/thread, 4 cols/thread.
// W double-buffered in registers (prefetch h+1 while computing h):
// 192 FMA-cycles per wave per h vs 3 L2-resident loads -> latency hidden.
__global__ __launch_bounds__(128) void qkv_kernel(
    const float* __restrict__ x,
    const float* __restrict__ WTq, const float* __restrict__ bq,
    const float* __restrict__ WTk, const float* __restrict__ bk,
    const float* __restrict__ WTv, const float* __restrict__ bv,
    float* __restrict__ Q, float* __restrict__ K, float* __restrict__ V)
{
    __shared__ float xs[32][HDIM];          // 16 KB
    const int r0 = blockIdx.x * 32;
    for (int i = threadIdx.x; i < 32 * HDIM / 4; i += 128) {
        const int r = i >> 5, jj = i & 31;
        int gr = r0 + r; if (gr >= N_NODES) gr = N_NODES - 1;
        *(float4*)&xs[r][jj * 4] = *(const float4*)&x[(size_t)gr * HDIM + jj * 4];
    }
    __syncthreads();
    const int cq = threadIdx.x & 31;        // column group (4 cols)
    const int rg = threadIdx.x >> 5;        // row group (8 rows): 0..3
    float4 aq[8], ak[8], av[8];
#pragma unroll
    for (int i = 0; i < 8; ++i) {
        aq[i] = make_float4(0.f, 0.f, 0.f, 0.f);
        ak[i] = make_float4(0.f, 0.f, 0.f, 0.f);
        av[i] = make_float4(0.f, 0.f, 0.f, 0.f);
    }
    const float4* wq4 = (const float4*)WTq + cq;   // row stride = 32 float4
    const float4* wk4 = (const float4*)WTk + cq;
    const float4* wv4 = (const float4*)WTv + cq;

    float4 wq0 = wq4[0], wk0 = wk4[0], wv0 = wv4[0];
#pragma unroll 4
    for (int h = 0; h < HDIM - 1; ++h) {
        // prefetch next h
        const float4 wq1 = wq4[(h + 1) * 32];
        const float4 wk1 = wk4[(h + 1) * 32];
        const float4 wv1 = wv4[(h + 1) * 32];
#pragma unroll
        for (int i = 0; i < 8; ++i) {
            const float xv = xs[rg * 8 + i][h];
            aq[i].x += wq0.x * xv; aq[i].y += wq0.y * xv;
            aq[i].z += wq0.z * xv; aq[i].w += wq0.w * xv;
            ak[i].x += wk0.x * xv; ak[i].y += wk0.y * xv;
            ak[i].z += wk0.z * xv; ak[i].w += wk0.w * xv;
            av[i].x += wv0.x * xv; av[i].y += wv0.y * xv;
            av[i].z += wv0.z * xv; av[i].w += wv0.w * xv;
        }
        wq0 = wq1; wk0 = wk1; wv0 = wv1;
    }
    // last h
#pragma unroll
    for (int i = 0; i < 8; ++i) {
        const float xv = xs[rg * 8 + i][HDIM - 1];
        aq[i].x += wq0.x * xv; aq[i].y += wq0.y * xv;
        aq[i].z += wq0.z * xv; aq[i].w += wq0.w * xv;
        ak[i].x += wk0.x * xv; ak[i].y += wk0.y * xv;
        ak[i].z += wk0.z * xv; ak[i].w += wk0.w * xv;
        av[i].x += wv0.x * xv; av[i].y += wv0.y * xv;
        av[i].z += wv0.z * xv; av[i].w += wv0.w * xv;
    }

    const float4 b_q = *(const float4*)&bq[cq * 4];
    const float4 b_k = *(const float4*)&bk[cq * 4];
    const float4 b_v = *(const float4*)&bv[cq * 4];
#pragma unroll
    for (int i = 0; i < 8; ++i) {
        const int gr = r0 + rg * 8 + i;
        if (gr < N_NODES) {
            const size_t base = (size_t)gr * HDIM + cq * 4;
            *(float4*)&Q[base] = make_float4(aq[i].x + b_q.x, aq[i].y + b_q.y,
                                             aq[i].z + b_q.z, aq[i].w + b_q.w);
            *(float4*)&K[base] = make_float4(ak[i].x + b_k.x, ak[i].y + b_k.y,
                                             ak[i].z + b_k.z, ak[i].w + b_k.w);
            *(float4*)&V[base] = make_float4(av[i].x + b_v.x, av[i].y + b_v.y,
                                             av[i].z + b_v.z, av[i].w + b_v.w);
        }
    }
}

// ---- Phase 2a: histogram of destination rows ----
__global__ __launch_bounds__(256) void hist_kernel(
    const int* __restrict__ ei, int* __restrict__ counts)
{
    const int e = blockIdx.x * 256 + threadIdx.x;
    if (e < E_EDGES) atomicAdd(&counts[ei[e]], 1);
}

// ---- Phase 2b: exclusive prefix scan (3 small kernels) ----
__global__ __launch_bounds__(256) void scan_partial_kernel(
    const int* __restrict__ counts, int* __restrict__ offs, int* __restrict__ aux)
{
    __shared__ int s[256];
    const int i = blockIdx.x * 256 + threadIdx.x;
    const int v = (i < N_NODES) ? counts[i] : 0;
    s[threadIdx.x] = v;
    __syncthreads();
    for (int d = 1; d < 256; d <<= 1) {
        int t = (threadIdx.x >= d) ? s[threadIdx.x - d] : 0;
        __syncthreads();
        s[threadIdx.x] += t;
        __syncthreads();
    }
    if (i < N_NODES) offs[i] = s[threadIdx.x] - v;   // exclusive within block
    if (threadIdx.x == 255) aux[blockIdx.x] = s[255];
}

__global__ __launch_bounds__(256) void scan_aux_kernel(int* __restrict__ aux)
{
    __shared__ int s[256];
    const int i = threadIdx.x;
    const int v = (i < SCAN_BLOCKS) ? aux[i] : 0;
    s[i] = v;
    __syncthreads();
    for (int d = 1; d < 256; d <<= 1) {
        int t = (i >= d) ? s[i - d] : 0;
        __syncthreads();
        s[i] += t;
        __syncthreads();
    }
    if (i < SCAN_BLOCKS) aux[i] = s[i] - v;          // exclusive
}

__global__ __launch_bounds__(256) void scan_add_kernel(
    int* __restrict__ offs, const int* __restrict__ aux, int* __restrict__ cursor)
{
    const int i = blockIdx.x * 256 + threadIdx.x;
    if (i < N_NODES) {
        const int o = offs[i] + aux[blockIdx.x];
        offs[i] = o;
        cursor[i] = o;
    }
}

// ---- Phase 2c: bin edges by destination row ----
__global__ __launch_bounds__(256) void bin_kernel(
    const int* __restrict__ ei, const float* __restrict__ ew,
    int* __restrict__ cursor, int* __restrict__ bcol, float* __restrict__ bew)
{
    const int e = blockIdx.x * 256 + threadIdx.x;
    if (e >= E_EDGES) return;
    const int row = ei[e];
    const int pos = atomicAdd(&cursor[row], 1);
    bcol[pos] = ei[E_EDGES + e];
    bew[pos]  = ew[e];
}

// ---- Phase 3: per-edge energy (one wave per row, Q row cached in regs) ----
__global__ __launch_bounds__(256) void energy_kernel(
    const float* __restrict__ Q, const float* __restrict__ K,
    const int* __restrict__ offs, const int* __restrict__ counts,
    const int* __restrict__ bcol, const float* __restrict__ bew,
    float* __restrict__ bp, float* __restrict__ blockmax)
{
    const int row  = (blockIdx.x * 256 + threadIdx.x) >> 6;
    const int lane = threadIdx.x & 63;
    const int start = offs[row], len = counts[row];
    const float2 q = *(const float2*)&Q[(size_t)row * HDIM + lane * 2];
    const float inv_scale = 0.08838834764831845f;  // 1/sqrt(128)
    float lmax = -3.4e38f;
    for (int j = 0; j < len; ++j) {
        const int   c = bcol[start + j];
        const float w = bew[start + j];
        float2 k = *(const float2*)&K[(size_t)c * HDIM + lane * 2];
        float d = q.x * k.x + q.y * k.y;
#pragma unroll
        for (int m = 32; m >= 1; m >>= 1) d += __shfl_xor(d, m);
        const float en = d * inv_scale * w;
        if (lane == 0) bp[start + j] = en;
        lmax = fmaxf(lmax, en);
    }
    __shared__ float sm[4];
    if (lane == 0) sm[threadIdx.x >> 6] = lmax;
    __syncthreads();
    if (threadIdx.x == 0)
        blockmax[blockIdx.x] = fmaxf(fmaxf(sm[0], sm[1]), fmaxf(sm[2], sm[3]));
}

__global__ __launch_bounds__(256) void reduce_max_kernel(
    const float* __restrict__ bm, int n, float* __restrict__ gmax)
{
    float m = -3.4e38f;
    for (int i = threadIdx.x; i < n; i += 256) m = fmaxf(m, bm[i]);
#pragma unroll
    for (int s = 32; s >= 1; s >>= 1) m = fmaxf(m, __shfl_xor(m, s));
    __shared__ float sm[4];
    if ((threadIdx.x & 63) == 0) sm[threadIdx.x >> 6] = m;
    __syncthreads();
    if (threadIdx.x == 0) *gmax = fmaxf(fmaxf(sm[0], sm[1]), fmaxf(sm[2], sm[3]));
}

// ---- Phase 4: p = exp(en - max), partial sums ----
__global__ __launch_bounds__(256) void expsum_kernel(
    float* __restrict__ bp, const float* __restrict__ gmax,
    float* __restrict__ blocksum)
{
    const float m = *gmax;
    const int e = blockIdx.x * 256 + threadIdx.x;
    float p = 0.f;
    if (e < E_EDGES) { p = __expf(bp[e] - m); bp[e] = p; }
#pragma unroll
    for (int s = 32; s >= 1; s >>= 1) p += __shfl_xor(p, s);
    __shared__ float sm[4];
    if ((threadIdx.x & 63) == 0) sm[threadIdx.x >> 6] = p;
    __syncthreads();
    if (threadIdx.x == 0) blocksum[blockIdx.x] = sm[0] + sm[1] + sm[2] + sm[3];
}

__global__ __launch_bounds__(256) void reduce_sum_kernel(
    const float* __restrict__ bs, int n, float* __restrict__ gsum)
{
    float v = 0.f;
    for (int i = threadIdx.x; i < n; i += 256) v += bs[i];
#pragma unroll
    for (int s = 32; s >= 1; s >>= 1) v += __shfl_xor(v, s);
    __shared__ float sm[4];
    if ((threadIdx.x & 63) == 0) sm[threadIdx.x >> 6] = v;
    __syncthreads();
    if (threadIdx.x == 0) *gsum = sm[0] + sm[1] + sm[2] + sm[3];
}

// ---- Phase 5: out[row] = sum_j V[bcol[j]] * p[j] / gsum  (no atomics) ----
__global__ __launch_bounds__(256) void accum_kernel(
    const float* __restrict__ V,
    const int* __restrict__ offs, const int* __restrict__ counts,
    const int* __restrict__ bcol, const float* __restrict__ bp,
    const float* __restrict__ gsum, float* __restrict__ out)
{
    const int row  = (blockIdx.x * 256 + threadIdx.x) >> 6;
    const int lane = threadIdx.x & 63;
    const float inv = 1.0f / *gsum;
    const int start = offs[row], len = counts[row];
    float ax = 0.f, ay = 0.f;
    for (int j = 0; j < len; ++j) {
        const int   c = bcol[start + j];
        const float w = bp[start + j] * inv;
        float2 v = *(const float2*)&V[(size_t)c * HDIM + lane * 2];
        ax += v.x * w;
        ay += v.y * w;
    }
    *(float2*)&out[(size_t)row * HDIM + lane * 2] = make_float2(ax, ay);
}

extern "C" void kernel_launch(void* const* d_in, const int* in_sizes, int n_in,
                              void* d_out, int out_size, void* d_ws, size_t ws_size,
                              hipStream_t stream)
{
    const float* x  = (const float*)d_in[0];
    const int*   ei = (const int*)d_in[1];
    const float* ew = (const float*)d_in[2];
    const float* Wq = (const float*)d_in[3];
    const float* bq = (const float*)d_in[4];
    const float* Wk = (const float*)d_in[5];
    const float* bk = (const float*)d_in[6];
    const float* Wv = (const float*)d_in[7];
    const float* bv = (const float*)d_in[8];
    float* out = (float*)d_out;

    float* ws = (float*)d_ws;
    float* Q       = ws;                                  // N*H
    float* K       = Q + (size_t)N_NODES * HDIM;          // N*H
    float* V       = K + (size_t)N_NODES * HDIM;          // N*H
    float* fp      = V + (size_t)N_NODES * HDIM;
    int*   counts  = (int*)fp;                            // N
    int*   offs    = counts + N_NODES;                    // N
    int*   cursor  = offs + N_NODES;                      // N
    int*   aux     = cursor + N_NODES;                    // SCAN_BLOCKS
    int*   bcol    = aux + 256;                           // E
    float* bew     = (float*)(bcol + E_EDGES);            // E
    float* bp      = bew + E_EDGES;                       // E
    float* blockmax= bp + E_EDGES;                        // ROW_BLOCKS
    float* blocksum= blockmax + ROW_BLOCKS;               // EDGE_BLOCKS
    float* gmax    = blocksum + EDGE_BLOCKS;              // 1
    float* gsum    = gmax + 1;                            // 1
    float* WTq     = gsum + 1;                            // 128*128
    float* WTk     = WTq + HDIM * HDIM;                   // 128*128
    float* WTv     = WTk + HDIM * HDIM;                   // 128*128

    hipMemsetAsync(counts, 0, N_NODES * sizeof(int), stream);

    transpose_w_kernel<<<48, 256, 0, stream>>>(Wq, Wk, Wv, WTq, WTk, WTv);
    qkv_kernel<<<QKV_BLOCKS, 128, 0, stream>>>(x, WTq, bq, WTk, bk, WTv, bv, Q, K, V);
    hist_kernel<<<EDGE_BLOCKS, 256, 0, stream>>>(ei, counts);
    scan_partial_kernel<<<SCAN_BLOCKS, 256, 0, stream>>>(counts, offs, aux);
    scan_aux_kernel<<<1, 256, 0, stream>>>(aux);
    scan_add_kernel<<<SCAN_BLOCKS, 256, 0, stream>>>(offs, aux, cursor);
    bin_kernel<<<EDGE_BLOCKS, 256, 0, stream>>>(ei, ew, cursor, bcol, bew);
    energy_kernel<<<ROW_BLOCKS, 256, 0, stream>>>(Q, K, offs, counts, bcol, bew, bp, blockmax);
    reduce_max_kernel<<<1, 256, 0, stream>>>(blockmax, ROW_BLOCKS, gmax);
    expsum_kernel<<<EDGE_BLOCKS, 256, 0, stream>>>(bp, gmax, blocksum);
    reduce_sum_kernel<<<1, 256, 0, stream>>>(blocksum, EDGE_BLOCKS, gsum);
    accum_kernel<<<ROW_BLOCKS, 256, 0, stream>>>(V, offs, counts, bcol, bp, gsum, out);
}

// Round 6
// 329.469 us; speedup vs baseline: 1.6192x; 1.0393x over previous
//
#include <hip/hip_runtime.h>
#include <hip/hip_bf16.h>

#define N_NODES 50000
#define E_EDGES 600000
#define HDIM    128

#define QKV_BLOCKS  ((N_NODES + 31) / 32)     // 1563 (32 rows/block, 128 thr)
#define EDGE_BLOCKS ((E_EDGES + 255) / 256)   // 2344
#define SCAN_BLOCKS ((N_NODES + 255) / 256)   // 196
#define ROW_BLOCKS  (N_NODES / 4)             // 12500 (4 waves/block, 1 wave/row)

__device__ __forceinline__ unsigned short f2bf(float f) {
    __hip_bfloat16 h = __float2bfloat16(f);
    return *reinterpret_cast<unsigned short*>(&h);
}

// ---- Phase 0: WT[h][c] = W[c][h] for the three weight matrices ----
__global__ __launch_bounds__(256) void transpose_w_kernel(
    const float* __restrict__ Wq, const float* __restrict__ Wk,
    const float* __restrict__ Wv,
    float* __restrict__ WTq, float* __restrict__ WTk, float* __restrict__ WTv)
{
    __shared__ float t[32][33];
    const int mat  = blockIdx.x >> 4;       // 0..2
    const int tile = blockIdx.x & 15;       // 4x4 grid of 32x32 tiles
    const int tr = (tile >> 2) * 32;        // c offset
    const int tc = (tile & 3) * 32;         // h offset
    const float* W  = (mat == 0) ? Wq  : (mat == 1) ? Wk  : Wv;
    float*       WT = (mat == 0) ? WTq : (mat == 1) ? WTk : WTv;
    const int lr = threadIdx.x >> 5;        // 0..7
    const int lc = threadIdx.x & 31;
#pragma unroll
    for (int i = 0; i < 4; ++i) {
        const int r = lr + i * 8;
        t[r][lc] = W[(size_t)(tr + r) * HDIM + tc + lc];
    }
    __syncthreads();
#pragma unroll
    for (int i = 0; i < 4; ++i) {
        const int r = lr + i * 8;
        WT[(size_t)(tc + r) * HDIM + tr + lc] = t[lc][r];
    }
}

// ---- Phase 1: Q(fp32) = x Wq^T + bq; Kb,Vb stored as bf16 (gather arrays) ----
// 128 threads, 32 rows/block, 8 rows/thread, 4 cols/thread.
// W double-buffered in registers (prefetch h+1 while computing h).
__global__ __launch_bounds__(128) void qkv_kernel(
    const float* __restrict__ x,
    const float* __restrict__ WTq, const float* __restrict__ bq,
    const float* __restrict__ WTk, const float* __restrict__ bk,
    const float* __restrict__ WTv, const float* __restrict__ bv,
    float* __restrict__ Q, unsigned short* __restrict__ Kb,
    unsigned short* __restrict__ Vb)
{
    __shared__ float xs[32][HDIM];          // 16 KB
    const int r0 = blockIdx.x * 32;
    for (int i = threadIdx.x; i < 32 * HDIM / 4; i += 128) {
        const int r = i >> 5, jj = i & 31;
        int gr = r0 + r; if (gr >= N_NODES) gr = N_NODES - 1;
        *(float4*)&xs[r][jj * 4] = *(const float4*)&x[(size_t)gr * HDIM + jj * 4];
    }
    __syncthreads();
    const int cq = threadIdx.x & 31;        // column group (4 cols)
    const int rg = threadIdx.x >> 5;        // row group (8 rows): 0..3
    float4 aq[8], ak[8], av[8];
#pragma unroll
    for (int i = 0; i < 8; ++i) {
        aq[i] = make_float4(0.f, 0.f, 0.f, 0.f);
        ak[i] = make_float4(0.f, 0.f, 0.f, 0.f);
        av[i] = make_float4(0.f, 0.f, 0.f, 0.f);
    }
    const float4* wq4 = (const float4*)WTq + cq;   // row stride = 32 float4
    const float4* wk4 = (const float4*)WTk + cq;
    const float4* wv4 = (const float4*)WTv + cq;

    float4 wq0 = wq4[0], wk0 = wk4[0], wv0 = wv4[0];
#pragma unroll 4
    for (int h = 0; h < HDIM - 1; ++h) {
        const float4 wq1 = wq4[(h + 1) * 32];
        const float4 wk1 = wk4[(h + 1) * 32];
        const float4 wv1 = wv4[(h + 1) * 32];
#pragma unroll
        for (int i = 0; i < 8; ++i) {
            const float xv = xs[rg * 8 + i][h];
            aq[i].x += wq0.x * xv; aq[i].y += wq0.y * xv;
            aq[i].z += wq0.z * xv; aq[i].w += wq0.w * xv;
            ak[i].x += wk0.x * xv; ak[i].y += wk0.y * xv;
            ak[i].z += wk0.z * xv; ak[i].w += wk0.w * xv;
            av[i].x += wv0.x * xv; av[i].y += wv0.y * xv;
            av[i].z += wv0.z * xv; av[i].w += wv0.w * xv;
        }
        wq0 = wq1; wk0 = wk1; wv0 = wv1;
    }
#pragma unroll
    for (int i = 0; i < 8; ++i) {
        const float xv = xs[rg * 8 + i][HDIM - 1];
        aq[i].x += wq0.x * xv; aq[i].y += wq0.y * xv;
        aq[i].z += wq0.z * xv; aq[i].w += wq0.w * xv;
        ak[i].x += wk0.x * xv; ak[i].y += wk0.y * xv;
        ak[i].z += wk0.z * xv; ak[i].w += wk0.w * xv;
        av[i].x += wv0.x * xv; av[i].y += wv0.y * xv;
        av[i].z += wv0.z * xv; av[i].w += wv0.w * xv;
    }

    const float4 b_q = *(const float4*)&bq[cq * 4];
    const float4 b_k = *(const float4*)&bk[cq * 4];
    const float4 b_v = *(const float4*)&bv[cq * 4];
#pragma unroll
    for (int i = 0; i < 8; ++i) {
        const int gr = r0 + rg * 8 + i;
        if (gr < N_NODES) {
            const size_t base = (size_t)gr * HDIM + cq * 4;
            *(float4*)&Q[base] = make_float4(aq[i].x + b_q.x, aq[i].y + b_q.y,
                                             aq[i].z + b_q.z, aq[i].w + b_q.w);
            ushort4 kb, vb;
            kb.x = f2bf(ak[i].x + b_k.x); kb.y = f2bf(ak[i].y + b_k.y);
            kb.z = f2bf(ak[i].z + b_k.z); kb.w = f2bf(ak[i].w + b_k.w);
            vb.x = f2bf(av[i].x + b_v.x); vb.y = f2bf(av[i].y + b_v.y);
            vb.z = f2bf(av[i].z + b_v.z); vb.w = f2bf(av[i].w + b_v.w);
            *(ushort4*)&Kb[base] = kb;
            *(ushort4*)&Vb[base] = vb;
        }
    }
}

// ---- Phase 2a: histogram of destination rows ----
__global__ __launch_bounds__(256) void hist_kernel(
    const int* __restrict__ ei, int* __restrict__ counts)
{
    const int e = blockIdx.x * 256 + threadIdx.x;
    if (e < E_EDGES) atomicAdd(&counts[ei[e]], 1);
}

// ---- Phase 2b: exclusive prefix scan (3 small kernels) ----
__global__ __launch_bounds__(256) void scan_partial_kernel(
    const int* __restrict__ counts, int* __restrict__ offs, int* __restrict__ aux)
{
    __shared__ int s[256];
    const int i = blockIdx.x * 256 + threadIdx.x;
    const int v = (i < N_NODES) ? counts[i] : 0;
    s[threadIdx.x] = v;
    __syncthreads();
    for (int d = 1; d < 256; d <<= 1) {
        int t = (threadIdx.x >= d) ? s[threadIdx.x - d] : 0;
        __syncthreads();
        s[threadIdx.x] += t;
        __syncthreads();
    }
    if (i < N_NODES) offs[i] = s[threadIdx.x] - v;   // exclusive within block
    if (threadIdx.x == 255) aux[blockIdx.x] = s[255];
}

__global__ __launch_bounds__(256) void scan_aux_kernel(int* __restrict__ aux)
{
    __shared__ int s[256];
    const int i = threadIdx.x;
    const int v = (i < SCAN_BLOCKS) ? aux[i] : 0;
    s[i] = v;
    __syncthreads();
    for (int d = 1; d < 256; d <<= 1) {
        int t = (i >= d) ? s[i - d] : 0;
        __syncthreads();
        s[i] += t;
        __syncthreads();
    }
    if (i < SCAN_BLOCKS) aux[i] = s[i] - v;          // exclusive
}

__global__ __launch_bounds__(256) void scan_add_kernel(
    int* __restrict__ offs, const int* __restrict__ aux, int* __restrict__ cursor)
{
    const int i = blockIdx.x * 256 + threadIdx.x;
    if (i < N_NODES) {
        const int o = offs[i] + aux[blockIdx.x];
        offs[i] = o;
        cursor[i] = o;
    }
}

// ---- Phase 2c: bin edges by destination row ----
__global__ __launch_bounds__(256) void bin_kernel(
    const int* __restrict__ ei, const float* __restrict__ ew,
    int* __restrict__ cursor, int* __restrict__ bcol, float* __restrict__ bew)
{
    const int e = blockIdx.x * 256 + threadIdx.x;
    if (e >= E_EDGES) return;
    const int row = ei[e];
    const int pos = atomicAdd(&cursor[row], 1);
    bcol[pos] = ei[E_EDGES + e];
    bew[pos]  = ew[e];
}

// ---- Phase 3: per-edge energy; K gathered as bf16 (2 per lane) ----
__global__ __launch_bounds__(256) void energy_kernel(
    const float* __restrict__ Q, const unsigned short* __restrict__ Kb,
    const int* __restrict__ offs, const int* __restrict__ counts,
    const int* __restrict__ bcol, const float* __restrict__ bew,
    float* __restrict__ bp, float* __restrict__ blockmax)
{
    const int row  = (blockIdx.x * 256 + threadIdx.x) >> 6;
    const int lane = threadIdx.x & 63;
    const int start = offs[row], len = counts[row];
    const float2 q = *(const float2*)&Q[(size_t)row * HDIM + lane * 2];
    const unsigned* kb32 = (const unsigned*)Kb;
    const float inv_scale = 0.08838834764831845f;  // 1/sqrt(128)
    float lmax = -3.4e38f;
    for (int j = 0; j < len; ++j) {
        const int   c = bcol[start + j];
        const float w = bew[start + j];
        const unsigned u = kb32[(size_t)c * 64 + lane];
        const float k0 = __uint_as_float(u << 16);
        const float k1 = __uint_as_float(u & 0xffff0000u);
        float d = q.x * k0 + q.y * k1;
#pragma unroll
        for (int m = 32; m >= 1; m >>= 1) d += __shfl_xor(d, m);
        const float en = d * inv_scale * w;
        if (lane == 0) bp[start + j] = en;
        lmax = fmaxf(lmax, en);
    }
    __shared__ float sm[4];
    if (lane == 0) sm[threadIdx.x >> 6] = lmax;
    __syncthreads();
    if (threadIdx.x == 0)
        blockmax[blockIdx.x] = fmaxf(fmaxf(sm[0], sm[1]), fmaxf(sm[2], sm[3]));
}

__global__ __launch_bounds__(256) void reduce_max_kernel(
    const float* __restrict__ bm, int n, float* __restrict__ gmax)
{
    float m = -3.4e38f;
    for (int i = threadIdx.x; i < n; i += 256) m = fmaxf(m, bm[i]);
#pragma unroll
    for (int s = 32; s >= 1; s >>= 1) m = fmaxf(m, __shfl_xor(m, s));
    __shared__ float sm[4];
    if ((threadIdx.x & 63) == 0) sm[threadIdx.x >> 6] = m;
    __syncthreads();
    if (threadIdx.x == 0) *gmax = fmaxf(fmaxf(sm[0], sm[1]), fmaxf(sm[2], sm[3]));
}

// ---- Phase 4: p = exp(en - max), partial sums ----
__global__ __launch_bounds__(256) void expsum_kernel(
    float* __restrict__ bp, const float* __restrict__ gmax,
    float* __restrict__ blocksum)
{
    const float m = *gmax;
    const int e = blockIdx.x * 256 + threadIdx.x;
    float p = 0.f;
    if (e < E_EDGES) { p = __expf(bp[e] - m); bp[e] = p; }
#pragma unroll
    for (int s = 32; s >= 1; s >>= 1) p += __shfl_xor(p, s);
    __shared__ float sm[4];
    if ((threadIdx.x & 63) == 0) sm[threadIdx.x >> 6] = p;
    __syncthreads();
    if (threadIdx.x == 0) blocksum[blockIdx.x] = sm[0] + sm[1] + sm[2] + sm[3];
}

__global__ __launch_bounds__(256) void reduce_sum_kernel(
    const float* __restrict__ bs, int n, float* __restrict__ gsum)
{
    float v = 0.f;
    for (int i = threadIdx.x; i < n; i += 256) v += bs[i];
#pragma unroll
    for (int s = 32; s >= 1; s >>= 1) v += __shfl_xor(v, s);
    __shared__ float sm[4];
    if ((threadIdx.x & 63) == 0) sm[threadIdx.x >> 6] = v;
    __syncthreads();
    if (threadIdx.x == 0) *gsum = sm[0] + sm[1] + sm[2] + sm[3];
}

// ---- Phase 5: out[row] = sum_j V[bcol[j]] * p[j] / gsum; V gathered bf16 ----
__global__ __launch_bounds__(256) void accum_kernel(
    const unsigned short* __restrict__ Vb,
    const int* __restrict__ offs, const int* __restrict__ counts,
    const int* __restrict__ bcol, const float* __restrict__ bp,
    const float* __restrict__ gsum, float* __restrict__ out)
{
    const int row  = (blockIdx.x * 256 + threadIdx.x) >> 6;
    const int lane = threadIdx.x & 63;
    const float inv = 1.0f / *gsum;
    const int start = offs[row], len = counts[row];
    const unsigned* vb32 = (const unsigned*)Vb;
    float ax = 0.f, ay = 0.f;
    for (int j = 0; j < len; ++j) {
        const int   c = bcol[start + j];
        const float w = bp[start + j] * inv;
        const unsigned u = vb32[(size_t)c * 64 + lane];
        ax += __uint_as_float(u << 16) * w;
        ay += __uint_as_float(u & 0xffff0000u) * w;
    }
    *(float2*)&out[(size_t)row * HDIM + lane * 2] = make_float2(ax, ay);
}

extern "C" void kernel_launch(void* const* d_in, const int* in_sizes, int n_in,
                              void* d_out, int out_size, void* d_ws, size_t ws_size,
                              hipStream_t stream)
{
    const float* x  = (const float*)d_in[0];
    const int*   ei = (const int*)d_in[1];
    const float* ew = (const float*)d_in[2];
    const float* Wq = (const float*)d_in[3];
    const float* bq = (const float*)d_in[4];
    const float* Wk = (const float*)d_in[5];
    const float* bk = (const float*)d_in[6];
    const float* Wv = (const float*)d_in[7];
    const float* bv = (const float*)d_in[8];
    float* out = (float*)d_out;

    float* ws = (float*)d_ws;
    float* Q       = ws;                                  // N*H fp32
    unsigned short* Kb = (unsigned short*)(Q + (size_t)N_NODES * HDIM);  // N*H bf16
    unsigned short* Vb = Kb + (size_t)N_NODES * HDIM;     // N*H bf16
    float* fp      = (float*)(Vb + (size_t)N_NODES * HDIM);
    int*   counts  = (int*)fp;                            // N
    int*   offs    = counts + N_NODES;                    // N
    int*   cursor  = offs + N_NODES;                      // N
    int*   aux     = cursor + N_NODES;                    // SCAN_BLOCKS
    int*   bcol    = aux + 256;                           // E
    float* bew     = (float*)(bcol + E_EDGES);            // E
    float* bp      = bew + E_EDGES;                       // E
    float* blockmax= bp + E_EDGES;                        // ROW_BLOCKS
    float* blocksum= blockmax + ROW_BLOCKS;               // EDGE_BLOCKS
    float* gmax    = blocksum + EDGE_BLOCKS;              // 1
    float* gsum    = gmax + 1;                            // 1
    float* WTq     = gsum + 1;                            // 128*128
    float* WTk     = WTq + HDIM * HDIM;                   // 128*128
    float* WTv     = WTk + HDIM * HDIM;                   // 128*128

    hipMemsetAsync(counts, 0, N_NODES * sizeof(int), stream);

    transpose_w_kernel<<<48, 256, 0, stream>>>(Wq, Wk, Wv, WTq, WTk, WTv);
    qkv_kernel<<<QKV_BLOCKS, 128, 0, stream>>>(x, WTq, bq, WTk, bk, WTv, bv, Q, Kb, Vb);
    hist_kernel<<<EDGE_BLOCKS, 256, 0, stream>>>(ei, counts);
    scan_partial_kernel<<<SCAN_BLOCKS, 256, 0, stream>>>(counts, offs, aux);
    scan_aux_kernel<<<1, 256, 0, stream>>>(aux);
    scan_add_kernel<<<SCAN_BLOCKS, 256, 0, stream>>>(offs, aux, cursor);
    bin_kernel<<<EDGE_BLOCKS, 256, 0, stream>>>(ei, ew, cursor, bcol, bew);
    energy_kernel<<<ROW_BLOCKS, 256, 0, stream>>>(Q, Kb, offs, counts, bcol, bew, bp, blockmax);
    reduce_max_kernel<<<1, 256, 0, stream>>>(blockmax, ROW_BLOCKS, gmax);
    expsum_kernel<<<EDGE_BLOCKS, 256, 0, stream>>>(bp, gmax, blocksum);
    reduce_sum_kernel<<<1, 256, 0, stream>>>(blocksum, EDGE_BLOCKS, gsum);
    accum_kernel<<<ROW_BLOCKS, 256, 0, stream>>>(Vb, offs, counts, bcol, bp, gsum, out);
}

// Round 7
// 286.127 us; speedup vs baseline: 1.8645x; 1.1515x over previous
//
#include <hip/hip_runtime.h>
#include <hip/hip_bf16.h>

#define N_NODES 50000
#define E_EDGES 600000
#define HDIM    128

#define QKV_BLOCKS  ((N_NODES + 31) / 32)     // 1563 (32 rows/block, 128 thr)
#define EDGE_BLOCKS ((E_EDGES + 255) / 256)   // 2344
#define SCAN_BLOCKS ((N_NODES + 255) / 256)   // 196
#define ROW_BLOCKS  (N_NODES / 4)             // 12500 (4 waves/block, 1 wave/row)

__device__ __forceinline__ unsigned short f2bf(float f) {
    __hip_bfloat16 h = __float2bfloat16(f);
    return *reinterpret_cast<unsigned short*>(&h);
}

// ---- Phase 0: WT[h][c] = W[c][h] for the three weight matrices ----
__global__ __launch_bounds__(256) void transpose_w_kernel(
    const float* __restrict__ Wq, const float* __restrict__ Wk,
    const float* __restrict__ Wv,
    float* __restrict__ WTq, float* __restrict__ WTk, float* __restrict__ WTv)
{
    __shared__ float t[32][33];
    const int mat  = blockIdx.x >> 4;       // 0..2
    const int tile = blockIdx.x & 15;       // 4x4 grid of 32x32 tiles
    const int tr = (tile >> 2) * 32;        // c offset
    const int tc = (tile & 3) * 32;         // h offset
    const float* W  = (mat == 0) ? Wq  : (mat == 1) ? Wk  : Wv;
    float*       WT = (mat == 0) ? WTq : (mat == 1) ? WTk : WTv;
    const int lr = threadIdx.x >> 5;        // 0..7
    const int lc = threadIdx.x & 31;
#pragma unroll
    for (int i = 0; i < 4; ++i) {
        const int r = lr + i * 8;
        t[r][lc] = W[(size_t)(tr + r) * HDIM + tc + lc];
    }
    __syncthreads();
#pragma unroll
    for (int i = 0; i < 4; ++i) {
        const int r = lr + i * 8;
        WT[(size_t)(tc + r) * HDIM + tr + lc] = t[lc][r];
    }
}

// ---- Phase 1: Q(fp32) = x Wq^T + bq; Kb,Vb stored as bf16 (gather arrays) ----
__global__ __launch_bounds__(128) void qkv_kernel(
    const float* __restrict__ x,
    const float* __restrict__ WTq, const float* __restrict__ bq,
    const float* __restrict__ WTk, const float* __restrict__ bk,
    const float* __restrict__ WTv, const float* __restrict__ bv,
    float* __restrict__ Q, unsigned short* __restrict__ Kb,
    unsigned short* __restrict__ Vb)
{
    __shared__ float xs[32][HDIM];          // 16 KB
    const int r0 = blockIdx.x * 32;
    for (int i = threadIdx.x; i < 32 * HDIM / 4; i += 128) {
        const int r = i >> 5, jj = i & 31;
        int gr = r0 + r; if (gr >= N_NODES) gr = N_NODES - 1;
        *(float4*)&xs[r][jj * 4] = *(const float4*)&x[(size_t)gr * HDIM + jj * 4];
    }
    __syncthreads();
    const int cq = threadIdx.x & 31;        // column group (4 cols)
    const int rg = threadIdx.x >> 5;        // row group (8 rows): 0..3
    float4 aq[8], ak[8], av[8];
#pragma unroll
    for (int i = 0; i < 8; ++i) {
        aq[i] = make_float4(0.f, 0.f, 0.f, 0.f);
        ak[i] = make_float4(0.f, 0.f, 0.f, 0.f);
        av[i] = make_float4(0.f, 0.f, 0.f, 0.f);
    }
    const float4* wq4 = (const float4*)WTq + cq;   // row stride = 32 float4
    const float4* wk4 = (const float4*)WTk + cq;
    const float4* wv4 = (const float4*)WTv + cq;

    float4 wq0 = wq4[0], wk0 = wk4[0], wv0 = wv4[0];
#pragma unroll 4
    for (int h = 0; h < HDIM - 1; ++h) {
        const float4 wq1 = wq4[(h + 1) * 32];
        const float4 wk1 = wk4[(h + 1) * 32];
        const float4 wv1 = wv4[(h + 1) * 32];
#pragma unroll
        for (int i = 0; i < 8; ++i) {
            const float xv = xs[rg * 8 + i][h];
            aq[i].x += wq0.x * xv; aq[i].y += wq0.y * xv;
            aq[i].z += wq0.z * xv; aq[i].w += wq0.w * xv;
            ak[i].x += wk0.x * xv; ak[i].y += wk0.y * xv;
            ak[i].z += wk0.z * xv; ak[i].w += wk0.w * xv;
            av[i].x += wv0.x * xv; av[i].y += wv0.y * xv;
            av[i].z += wv0.z * xv; av[i].w += wv0.w * xv;
        }
        wq0 = wq1; wk0 = wk1; wv0 = wv1;
    }
#pragma unroll
    for (int i = 0; i < 8; ++i) {
        const float xv = xs[rg * 8 + i][HDIM - 1];
        aq[i].x += wq0.x * xv; aq[i].y += wq0.y * xv;
        aq[i].z += wq0.z * xv; aq[i].w += wq0.w * xv;
        ak[i].x += wk0.x * xv; ak[i].y += wk0.y * xv;
        ak[i].z += wk0.z * xv; ak[i].w += wk0.w * xv;
        av[i].x += wv0.x * xv; av[i].y += wv0.y * xv;
        av[i].z += wv0.z * xv; av[i].w += wv0.w * xv;
    }

    const float4 b_q = *(const float4*)&bq[cq * 4];
    const float4 b_k = *(const float4*)&bk[cq * 4];
    const float4 b_v = *(const float4*)&bv[cq * 4];
#pragma unroll
    for (int i = 0; i < 8; ++i) {
        const int gr = r0 + rg * 8 + i;
        if (gr < N_NODES) {
            const size_t base = (size_t)gr * HDIM + cq * 4;
            *(float4*)&Q[base] = make_float4(aq[i].x + b_q.x, aq[i].y + b_q.y,
                                             aq[i].z + b_q.z, aq[i].w + b_q.w);
            ushort4 kb, vb;
            kb.x = f2bf(ak[i].x + b_k.x); kb.y = f2bf(ak[i].y + b_k.y);
            kb.z = f2bf(ak[i].z + b_k.z); kb.w = f2bf(ak[i].w + b_k.w);
            vb.x = f2bf(av[i].x + b_v.x); vb.y = f2bf(av[i].y + b_v.y);
            vb.z = f2bf(av[i].z + b_v.z); vb.w = f2bf(av[i].w + b_v.w);
            *(ushort4*)&Kb[base] = kb;
            *(ushort4*)&Vb[base] = vb;
        }
    }
}

// ---- Phase 2a: histogram of destination rows ----
__global__ __launch_bounds__(256) void hist_kernel(
    const int* __restrict__ ei, int* __restrict__ counts)
{
    const int e = blockIdx.x * 256 + threadIdx.x;
    if (e < E_EDGES) atomicAdd(&counts[ei[e]], 1);
}

// ---- Phase 2b: exclusive prefix scan (3 small kernels) ----
__global__ __launch_bounds__(256) void scan_partial_kernel(
    const int* __restrict__ counts, int* __restrict__ offs, int* __restrict__ aux)
{
    __shared__ int s[256];
    const int i = blockIdx.x * 256 + threadIdx.x;
    const int v = (i < N_NODES) ? counts[i] : 0;
    s[threadIdx.x] = v;
    __syncthreads();
    for (int d = 1; d < 256; d <<= 1) {
        int t = (threadIdx.x >= d) ? s[threadIdx.x - d] : 0;
        __syncthreads();
        s[threadIdx.x] += t;
        __syncthreads();
    }
    if (i < N_NODES) offs[i] = s[threadIdx.x] - v;   // exclusive within block
    if (threadIdx.x == 255) aux[blockIdx.x] = s[255];
}

__global__ __launch_bounds__(256) void scan_aux_kernel(int* __restrict__ aux)
{
    __shared__ int s[256];
    const int i = threadIdx.x;
    const int v = (i < SCAN_BLOCKS) ? aux[i] : 0;
    s[i] = v;
    __syncthreads();
    for (int d = 1; d < 256; d <<= 1) {
        int t = (i >= d) ? s[i - d] : 0;
        __syncthreads();
        s[i] += t;
        __syncthreads();
    }
    if (i < SCAN_BLOCKS) aux[i] = s[i] - v;          // exclusive
}

__global__ __launch_bounds__(256) void scan_add_kernel(
    int* __restrict__ offs, const int* __restrict__ aux, int* __restrict__ cursor)
{
    const int i = blockIdx.x * 256 + threadIdx.x;
    if (i < N_NODES) {
        const int o = offs[i] + aux[blockIdx.x];
        offs[i] = o;
        cursor[i] = o;
    }
}

// ---- Phase 2c: bin edges by destination row ----
__global__ __launch_bounds__(256) void bin_kernel(
    const int* __restrict__ ei, const float* __restrict__ ew,
    int* __restrict__ cursor, int* __restrict__ bcol, float* __restrict__ bew)
{
    const int e = blockIdx.x * 256 + threadIdx.x;
    if (e >= E_EDGES) return;
    const int row = ei[e];
    const int pos = atomicAdd(&cursor[row], 1);
    bcol[pos] = ei[E_EDGES + e];
    bew[pos]  = ew[e];
}

// ---- Phase 3: per-edge energy; 4 edges/wave, 16 lanes/edge ----
// Lane holds Q[row][sl*8..sl*8+7] in regs; gathers uint4 (8 bf16) of K.
// 4 independent row-gathers in flight; 4-shfl reduce shared by 4 edges.
__global__ __launch_bounds__(256) void energy_kernel(
    const float* __restrict__ Q, const unsigned short* __restrict__ Kb,
    const int* __restrict__ offs, const int* __restrict__ counts,
    const int* __restrict__ bcol, const float* __restrict__ bew,
    float* __restrict__ bp, float* __restrict__ blockmax)
{
    const int row  = (blockIdx.x * 256 + threadIdx.x) >> 6;
    const int lane = threadIdx.x & 63;
    const int eg   = lane >> 4;     // edge group 0..3
    const int sl   = lane & 15;     // sub-lane in group
    const int start = offs[row], len = counts[row];
    const float4 q0 = *(const float4*)&Q[(size_t)row * HDIM + sl * 8];
    const float4 q1 = *(const float4*)&Q[(size_t)row * HDIM + sl * 8 + 4];
    const uint4* kb128 = (const uint4*)Kb;   // one row = 16 uint4
    const float inv_scale = 0.08838834764831845f;  // 1/sqrt(128)
    float lmax = -3.4e38f;
    for (int j0 = 0; j0 < len; j0 += 4) {
        const int  jj    = j0 + eg;
        const bool valid = jj < len;
        const int  e     = start + (valid ? jj : 0);
        const int  c     = bcol[e];
        const float w    = bew[e];
        const uint4 u = kb128[(size_t)c * 16 + sl];
        const float k0 = __uint_as_float(u.x << 16);
        const float k1 = __uint_as_float(u.x & 0xffff0000u);
        const float k2 = __uint_as_float(u.y << 16);
        const float k3 = __uint_as_float(u.y & 0xffff0000u);
        const float k4 = __uint_as_float(u.z << 16);
        const float k5 = __uint_as_float(u.z & 0xffff0000u);
        const float k6 = __uint_as_float(u.w << 16);
        const float k7 = __uint_as_float(u.w & 0xffff0000u);
        float d = q0.x * k0 + q0.y * k1 + q0.z * k2 + q0.w * k3
                + q1.x * k4 + q1.y * k5 + q1.z * k6 + q1.w * k7;
#pragma unroll
        for (int m = 8; m >= 1; m >>= 1) d += __shfl_xor(d, m);
        const float en = d * inv_scale * w;
        if (valid) {
            lmax = fmaxf(lmax, en);
            if (sl == 0) bp[e] = en;
        }
    }
#pragma unroll
    for (int m = 32; m >= 1; m >>= 1) lmax = fmaxf(lmax, __shfl_xor(lmax, m));
    __shared__ float sm[4];
    if (lane == 0) sm[threadIdx.x >> 6] = lmax;
    __syncthreads();
    if (threadIdx.x == 0)
        blockmax[blockIdx.x] = fmaxf(fmaxf(sm[0], sm[1]), fmaxf(sm[2], sm[3]));
}

__global__ __launch_bounds__(256) void reduce_max_kernel(
    const float* __restrict__ bm, int n, float* __restrict__ gmax)
{
    float m = -3.4e38f;
    for (int i = threadIdx.x; i < n; i += 256) m = fmaxf(m, bm[i]);
#pragma unroll
    for (int s = 32; s >= 1; s >>= 1) m = fmaxf(m, __shfl_xor(m, s));
    __shared__ float sm[4];
    if ((threadIdx.x & 63) == 0) sm[threadIdx.x >> 6] = m;
    __syncthreads();
    if (threadIdx.x == 0) *gmax = fmaxf(fmaxf(sm[0], sm[1]), fmaxf(sm[2], sm[3]));
}

// ---- Phase 4: p = exp(en - max), partial sums ----
__global__ __launch_bounds__(256) void expsum_kernel(
    float* __restrict__ bp, const float* __restrict__ gmax,
    float* __restrict__ blocksum)
{
    const float m = *gmax;
    const int e = blockIdx.x * 256 + threadIdx.x;
    float p = 0.f;
    if (e < E_EDGES) { p = __expf(bp[e] - m); bp[e] = p; }
#pragma unroll
    for (int s = 32; s >= 1; s >>= 1) p += __shfl_xor(p, s);
    __shared__ float sm[4];
    if ((threadIdx.x & 63) == 0) sm[threadIdx.x >> 6] = p;
    __syncthreads();
    if (threadIdx.x == 0) blocksum[blockIdx.x] = sm[0] + sm[1] + sm[2] + sm[3];
}

__global__ __launch_bounds__(256) void reduce_sum_kernel(
    const float* __restrict__ bs, int n, float* __restrict__ gsum)
{
    float v = 0.f;
    for (int i = threadIdx.x; i < n; i += 256) v += bs[i];
#pragma unroll
    for (int s = 32; s >= 1; s >>= 1) v += __shfl_xor(v, s);
    __shared__ float sm[4];
    if ((threadIdx.x & 63) == 0) sm[threadIdx.x >> 6] = v;
    __syncthreads();
    if (threadIdx.x == 0) *gsum = sm[0] + sm[1] + sm[2] + sm[3];
}

// ---- Phase 5: out[row] = sum_j V[bcol[j]] * p[j] / gsum; V gathered bf16 ----
__global__ __launch_bounds__(256) void accum_kernel(
    const unsigned short* __restrict__ Vb,
    const int* __restrict__ offs, const int* __restrict__ counts,
    const int* __restrict__ bcol, const float* __restrict__ bp,
    const float* __restrict__ gsum, float* __restrict__ out)
{
    const int row  = (blockIdx.x * 256 + threadIdx.x) >> 6;
    const int lane = threadIdx.x & 63;
    const float inv = 1.0f / *gsum;
    const int start = offs[row], len = counts[row];
    const unsigned* vb32 = (const unsigned*)Vb;
    float ax = 0.f, ay = 0.f;
    for (int j = 0; j < len; ++j) {
        const int   c = bcol[start + j];
        const float w = bp[start + j] * inv;
        const unsigned u = vb32[(size_t)c * 64 + lane];
        ax += __uint_as_float(u << 16) * w;
        ay += __uint_as_float(u & 0xffff0000u) * w;
    }
    *(float2*)&out[(size_t)row * HDIM + lane * 2] = make_float2(ax, ay);
}

extern "C" void kernel_launch(void* const* d_in, const int* in_sizes, int n_in,
                              void* d_out, int out_size, void* d_ws, size_t ws_size,
                              hipStream_t stream)
{
    const float* x  = (const float*)d_in[0];
    const int*   ei = (const int*)d_in[1];
    const float* ew = (const float*)d_in[2];
    const float* Wq = (const float*)d_in[3];
    const float* bq = (const float*)d_in[4];
    const float* Wk = (const float*)d_in[5];
    const float* bk = (const float*)d_in[6];
    const float* Wv = (const float*)d_in[7];
    const float* bv = (const float*)d_in[8];
    float* out = (float*)d_out;

    float* ws = (float*)d_ws;
    float* Q       = ws;                                  // N*H fp32
    unsigned short* Kb = (unsigned short*)(Q + (size_t)N_NODES * HDIM);  // N*H bf16
    unsigned short* Vb = Kb + (size_t)N_NODES * HDIM;     // N*H bf16
    float* fp      = (float*)(Vb + (size_t)N_NODES * HDIM);
    int*   counts  = (int*)fp;                            // N
    int*   offs    = counts + N_NODES;                    // N
    int*   cursor  = offs + N_NODES;                      // N
    int*   aux     = cursor + N_NODES;                    // SCAN_BLOCKS
    int*   bcol    = aux + 256;                           // E
    float* bew     = (float*)(bcol + E_EDGES);            // E
    float* bp      = bew + E_EDGES;                       // E
    float* blockmax= bp + E_EDGES;                        // ROW_BLOCKS
    float* blocksum= blockmax + ROW_BLOCKS;               // EDGE_BLOCKS
    float* gmax    = blocksum + EDGE_BLOCKS;              // 1
    float* gsum    = gmax + 1;                            // 1
    float* WTq     = gsum + 1;                            // 128*128
    float* WTk     = WTq + HDIM * HDIM;                   // 128*128
    float* WTv     = WTk + HDIM * HDIM;                   // 128*128

    hipMemsetAsync(counts, 0, N_NODES * sizeof(int), stream);

    transpose_w_kernel<<<48, 256, 0, stream>>>(Wq, Wk, Wv, WTq, WTk, WTv);
    qkv_kernel<<<QKV_BLOCKS, 128, 0, stream>>>(x, WTq, bq, WTk, bk, WTv, bv, Q, Kb, Vb);
    hist_kernel<<<EDGE_BLOCKS, 256, 0, stream>>>(ei, counts);
    scan_partial_kernel<<<SCAN_BLOCKS, 256, 0, stream>>>(counts, offs, aux);
    scan_aux_kernel<<<1, 256, 0, stream>>>(aux);
    scan_add_kernel<<<SCAN_BLOCKS, 256, 0, stream>>>(offs, aux, cursor);
    bin_kernel<<<EDGE_BLOCKS, 256, 0, stream>>>(ei, ew, cursor, bcol, bew);
    energy_kernel<<<ROW_BLOCKS, 256, 0, stream>>>(Q, Kb, offs, counts, bcol, bew, bp, blockmax);
    reduce_max_kernel<<<1, 256, 0, stream>>>(blockmax, ROW_BLOCKS, gmax);
    expsum_kernel<<<EDGE_BLOCKS, 256, 0, stream>>>(bp, gmax, blocksum);
    reduce_sum_kernel<<<1, 256, 0, stream>>>(blocksum, EDGE_BLOCKS, gsum);
    accum_kernel<<<ROW_BLOCKS, 256, 0, stream>>>(Vb, offs, counts, bcol, bp, gsum, out);
}

// Round 8
// 281.894 us; speedup vs baseline: 1.8925x; 1.0150x over previous
//
#include <hip/hip_runtime.h>
#include <hip/hip_bf16.h>

#define N_NODES 50000
#define E_EDGES 600000
#define HDIM    128

#define QKV_BLOCKS  ((N_NODES + 63) / 64)     // 782 (64 rows/block, 256 thr)
#define EDGE_BLOCKS ((E_EDGES + 255) / 256)   // 2344
#define SCAN_BLOCKS ((N_NODES + 255) / 256)   // 196
#define ROW_BLOCKS  (N_NODES / 4)             // 12500 (4 waves/block, 1 wave/row)

__device__ __forceinline__ unsigned short f2bf(float f) {
    __hip_bfloat16 h = __float2bfloat16(f);
    return *reinterpret_cast<unsigned short*>(&h);
}

// ---- Phase 0: WT[h][c] = W[c][h] for the three weight matrices ----
__global__ __launch_bounds__(256) void transpose_w_kernel(
    const float* __restrict__ Wq, const float* __restrict__ Wk,
    const float* __restrict__ Wv,
    float* __restrict__ WTq, float* __restrict__ WTk, float* __restrict__ WTv)
{
    __shared__ float t[32][33];
    const int mat  = blockIdx.x >> 4;       // 0..2
    const int tile = blockIdx.x & 15;       // 4x4 grid of 32x32 tiles
    const int tr = (tile >> 2) * 32;        // c offset
    const int tc = (tile & 3) * 32;         // h offset
    const float* W  = (mat == 0) ? Wq  : (mat == 1) ? Wk  : Wv;
    float*       WT = (mat == 0) ? WTq : (mat == 1) ? WTk : WTv;
    const int lr = threadIdx.x >> 5;        // 0..7
    const int lc = threadIdx.x & 31;
#pragma unroll
    for (int i = 0; i < 4; ++i) {
        const int r = lr + i * 8;
        t[r][lc] = W[(size_t)(tr + r) * HDIM + tc + lc];
    }
    __syncthreads();
#pragma unroll
    for (int i = 0; i < 4; ++i) {
        const int r = lr + i * 8;
        WT[(size_t)(tc + r) * HDIM + tr + lc] = t[lc][r];
    }
}

// ---- Phase 1: Q(fp32) = x Wq^T + bq; Kb,Vb stored bf16 ----
// 256 threads, 64 rows/block, 8 rows/thread, 4 cols/thread.
// Depth-2 register prefetch of W (h+2 in flight while computing h).
__global__ __launch_bounds__(256) void qkv_kernel(
    const float* __restrict__ x,
    const float* __restrict__ WTq, const float* __restrict__ bq,
    const float* __restrict__ WTk, const float* __restrict__ bk,
    const float* __restrict__ WTv, const float* __restrict__ bv,
    float* __restrict__ Q, unsigned short* __restrict__ Kb,
    unsigned short* __restrict__ Vb)
{
    __shared__ float xs[64][HDIM];          // 32 KB
    const int r0 = blockIdx.x * 64;
    for (int i = threadIdx.x; i < 64 * HDIM / 4; i += 256) {
        const int r = i >> 5, jj = i & 31;
        int gr = r0 + r; if (gr >= N_NODES) gr = N_NODES - 1;
        *(float4*)&xs[r][jj * 4] = *(const float4*)&x[(size_t)gr * HDIM + jj * 4];
    }
    __syncthreads();
    const int cq = threadIdx.x & 31;        // column group (4 cols)
    const int rg = threadIdx.x >> 5;        // row group (8 rows): 0..7
    float4 aq[8], ak[8], av[8];
#pragma unroll
    for (int i = 0; i < 8; ++i) {
        aq[i] = make_float4(0.f, 0.f, 0.f, 0.f);
        ak[i] = make_float4(0.f, 0.f, 0.f, 0.f);
        av[i] = make_float4(0.f, 0.f, 0.f, 0.f);
    }
    const float4* wq4 = (const float4*)WTq + cq;   // row stride = 32 float4
    const float4* wk4 = (const float4*)WTk + cq;
    const float4* wv4 = (const float4*)WTv + cq;

    float4 wqA = wq4[0],  wkA = wk4[0],  wvA = wv4[0];
    float4 wqB = wq4[32], wkB = wk4[32], wvB = wv4[32];
#pragma unroll 2
    for (int h = 0; h < HDIM - 2; ++h) {
        const float4 wqC = wq4[(h + 2) * 32];
        const float4 wkC = wk4[(h + 2) * 32];
        const float4 wvC = wv4[(h + 2) * 32];
#pragma unroll
        for (int i = 0; i < 8; ++i) {
            const float xv = xs[rg * 8 + i][h];
            aq[i].x += wqA.x * xv; aq[i].y += wqA.y * xv;
            aq[i].z += wqA.z * xv; aq[i].w += wqA.w * xv;
            ak[i].x += wkA.x * xv; ak[i].y += wkA.y * xv;
            ak[i].z += wkA.z * xv; ak[i].w += wkA.w * xv;
            av[i].x += wvA.x * xv; av[i].y += wvA.y * xv;
            av[i].z += wvA.z * xv; av[i].w += wvA.w * xv;
        }
        wqA = wqB; wkA = wkB; wvA = wvB;
        wqB = wqC; wkB = wkC; wvB = wvC;
    }
    // tail h = 126 (A), h = 127 (B)
#pragma unroll
    for (int i = 0; i < 8; ++i) {
        const float xv = xs[rg * 8 + i][HDIM - 2];
        aq[i].x += wqA.x * xv; aq[i].y += wqA.y * xv;
        aq[i].z += wqA.z * xv; aq[i].w += wqA.w * xv;
        ak[i].x += wkA.x * xv; ak[i].y += wkA.y * xv;
        ak[i].z += wkA.z * xv; ak[i].w += wkA.w * xv;
        av[i].x += wvA.x * xv; av[i].y += wvA.y * xv;
        av[i].z += wvA.z * xv; av[i].w += wvA.w * xv;
    }
#pragma unroll
    for (int i = 0; i < 8; ++i) {
        const float xv = xs[rg * 8 + i][HDIM - 1];
        aq[i].x += wqB.x * xv; aq[i].y += wqB.y * xv;
        aq[i].z += wqB.z * xv; aq[i].w += wqB.w * xv;
        ak[i].x += wkB.x * xv; ak[i].y += wkB.y * xv;
        ak[i].z += wkB.z * xv; ak[i].w += wkB.w * xv;
        av[i].x += wvB.x * xv; av[i].y += wvB.y * xv;
        av[i].z += wvB.z * xv; av[i].w += wvB.w * xv;
    }

    const float4 b_q = *(const float4*)&bq[cq * 4];
    const float4 b_k = *(const float4*)&bk[cq * 4];
    const float4 b_v = *(const float4*)&bv[cq * 4];
#pragma unroll
    for (int i = 0; i < 8; ++i) {
        const int gr = r0 + rg * 8 + i;
        if (gr < N_NODES) {
            const size_t base = (size_t)gr * HDIM + cq * 4;
            *(float4*)&Q[base] = make_float4(aq[i].x + b_q.x, aq[i].y + b_q.y,
                                             aq[i].z + b_q.z, aq[i].w + b_q.w);
            ushort4 kb, vb;
            kb.x = f2bf(ak[i].x + b_k.x); kb.y = f2bf(ak[i].y + b_k.y);
            kb.z = f2bf(ak[i].z + b_k.z); kb.w = f2bf(ak[i].w + b_k.w);
            vb.x = f2bf(av[i].x + b_v.x); vb.y = f2bf(av[i].y + b_v.y);
            vb.z = f2bf(av[i].z + b_v.z); vb.w = f2bf(av[i].w + b_v.w);
            *(ushort4*)&Kb[base] = kb;
            *(ushort4*)&Vb[base] = vb;
        }
    }
}

// ---- Phase 2a: histogram of destination rows ----
__global__ __launch_bounds__(256) void hist_kernel(
    const int* __restrict__ ei, int* __restrict__ counts)
{
    const int e = blockIdx.x * 256 + threadIdx.x;
    if (e < E_EDGES) atomicAdd(&counts[ei[e]], 1);
}

// ---- Phase 2b: exclusive prefix scan (3 small kernels) ----
__global__ __launch_bounds__(256) void scan_partial_kernel(
    const int* __restrict__ counts, int* __restrict__ offs, int* __restrict__ aux)
{
    __shared__ int s[256];
    const int i = blockIdx.x * 256 + threadIdx.x;
    const int v = (i < N_NODES) ? counts[i] : 0;
    s[threadIdx.x] = v;
    __syncthreads();
    for (int d = 1; d < 256; d <<= 1) {
        int t = (threadIdx.x >= d) ? s[threadIdx.x - d] : 0;
        __syncthreads();
        s[threadIdx.x] += t;
        __syncthreads();
    }
    if (i < N_NODES) offs[i] = s[threadIdx.x] - v;   // exclusive within block
    if (threadIdx.x == 255) aux[blockIdx.x] = s[255];
}

__global__ __launch_bounds__(256) void scan_aux_kernel(int* __restrict__ aux)
{
    __shared__ int s[256];
    const int i = threadIdx.x;
    const int v = (i < SCAN_BLOCKS) ? aux[i] : 0;
    s[i] = v;
    __syncthreads();
    for (int d = 1; d < 256; d <<= 1) {
        int t = (i >= d) ? s[i - d] : 0;
        __syncthreads();
        s[i] += t;
        __syncthreads();
    }
    if (i < SCAN_BLOCKS) aux[i] = s[i] - v;          // exclusive
}

__global__ __launch_bounds__(256) void scan_add_kernel(
    int* __restrict__ offs, const int* __restrict__ aux, int* __restrict__ cursor)
{
    const int i = blockIdx.x * 256 + threadIdx.x;
    if (i < N_NODES) {
        const int o = offs[i] + aux[blockIdx.x];
        offs[i] = o;
        cursor[i] = o;
    }
}

// ---- Phase 2c: bin edges by destination row ----
__global__ __launch_bounds__(256) void bin_kernel(
    const int* __restrict__ ei, const float* __restrict__ ew,
    int* __restrict__ cursor, int* __restrict__ bcol, float* __restrict__ bew)
{
    const int e = blockIdx.x * 256 + threadIdx.x;
    if (e >= E_EDGES) return;
    const int row = ei[e];
    const int pos = atomicAdd(&cursor[row], 1);
    bcol[pos] = ei[E_EDGES + e];
    bew[pos]  = ew[e];
}

// ---- Phase 3: per-edge energy; 4 edges/wave, 16 lanes/edge ----
__global__ __launch_bounds__(256) void energy_kernel(
    const float* __restrict__ Q, const unsigned short* __restrict__ Kb,
    const int* __restrict__ offs, const int* __restrict__ counts,
    const int* __restrict__ bcol, const float* __restrict__ bew,
    float* __restrict__ bp, float* __restrict__ blockmax)
{
    const int row  = (blockIdx.x * 256 + threadIdx.x) >> 6;
    const int lane = threadIdx.x & 63;
    const int eg   = lane >> 4;     // edge group 0..3
    const int sl   = lane & 15;     // sub-lane in group
    const int start = offs[row], len = counts[row];
    const float4 q0 = *(const float4*)&Q[(size_t)row * HDIM + sl * 8];
    const float4 q1 = *(const float4*)&Q[(size_t)row * HDIM + sl * 8 + 4];
    const uint4* kb128 = (const uint4*)Kb;   // one row = 16 uint4
    const float inv_scale = 0.08838834764831845f;  // 1/sqrt(128)
    float lmax = -3.4e38f;
    for (int j0 = 0; j0 < len; j0 += 4) {
        const int  jj    = j0 + eg;
        const bool valid = jj < len;
        const int  e     = start + (valid ? jj : 0);
        const int  c     = bcol[e];
        const float w    = bew[e];
        const uint4 u = kb128[(size_t)c * 16 + sl];
        const float k0 = __uint_as_float(u.x << 16);
        const float k1 = __uint_as_float(u.x & 0xffff0000u);
        const float k2 = __uint_as_float(u.y << 16);
        const float k3 = __uint_as_float(u.y & 0xffff0000u);
        const float k4 = __uint_as_float(u.z << 16);
        const float k5 = __uint_as_float(u.z & 0xffff0000u);
        const float k6 = __uint_as_float(u.w << 16);
        const float k7 = __uint_as_float(u.w & 0xffff0000u);
        float d = q0.x * k0 + q0.y * k1 + q0.z * k2 + q0.w * k3
                + q1.x * k4 + q1.y * k5 + q1.z * k6 + q1.w * k7;
#pragma unroll
        for (int m = 8; m >= 1; m >>= 1) d += __shfl_xor(d, m);
        const float en = d * inv_scale * w;
        if (valid) {
            lmax = fmaxf(lmax, en);
            if (sl == 0) bp[e] = en;
        }
    }
#pragma unroll
    for (int m = 32; m >= 1; m >>= 1) lmax = fmaxf(lmax, __shfl_xor(lmax, m));
    __shared__ float sm[4];
    if (lane == 0) sm[threadIdx.x >> 6] = lmax;
    __syncthreads();
    if (threadIdx.x == 0)
        blockmax[blockIdx.x] = fmaxf(fmaxf(sm[0], sm[1]), fmaxf(sm[2], sm[3]));
}

__global__ __launch_bounds__(256) void reduce_max_kernel(
    const float* __restrict__ bm, int n, float* __restrict__ gmax)
{
    float m = -3.4e38f;
    for (int i = threadIdx.x; i < n; i += 256) m = fmaxf(m, bm[i]);
#pragma unroll
    for (int s = 32; s >= 1; s >>= 1) m = fmaxf(m, __shfl_xor(m, s));
    __shared__ float sm[4];
    if ((threadIdx.x & 63) == 0) sm[threadIdx.x >> 6] = m;
    __syncthreads();
    if (threadIdx.x == 0) *gmax = fmaxf(fmaxf(sm[0], sm[1]), fmaxf(sm[2], sm[3]));
}

// ---- Phase 4: p = exp(en - max), partial sums ----
__global__ __launch_bounds__(256) void expsum_kernel(
    float* __restrict__ bp, const float* __restrict__ gmax,
    float* __restrict__ blocksum)
{
    const float m = *gmax;
    const int e = blockIdx.x * 256 + threadIdx.x;
    float p = 0.f;
    if (e < E_EDGES) { p = __expf(bp[e] - m); bp[e] = p; }
#pragma unroll
    for (int s = 32; s >= 1; s >>= 1) p += __shfl_xor(p, s);
    __shared__ float sm[4];
    if ((threadIdx.x & 63) == 0) sm[threadIdx.x >> 6] = p;
    __syncthreads();
    if (threadIdx.x == 0) blocksum[blockIdx.x] = sm[0] + sm[1] + sm[2] + sm[3];
}

__global__ __launch_bounds__(256) void reduce_sum_kernel(
    const float* __restrict__ bs, int n, float* __restrict__ gsum)
{
    float v = 0.f;
    for (int i = threadIdx.x; i < n; i += 256) v += bs[i];
#pragma unroll
    for (int s = 32; s >= 1; s >>= 1) v += __shfl_xor(v, s);
    __shared__ float sm[4];
    if ((threadIdx.x & 63) == 0) sm[threadIdx.x >> 6] = v;
    __syncthreads();
    if (threadIdx.x == 0) *gsum = sm[0] + sm[1] + sm[2] + sm[3];
}

// ---- Phase 5: out[row] = sum_j V[bcol[j]] * p[j] / gsum; V gathered bf16 ----
__global__ __launch_bounds__(256) void accum_kernel(
    const unsigned short* __restrict__ Vb,
    const int* __restrict__ offs, const int* __restrict__ counts,
    const int* __restrict__ bcol, const float* __restrict__ bp,
    const float* __restrict__ gsum, float* __restrict__ out)
{
    const int row  = (blockIdx.x * 256 + threadIdx.x) >> 6;
    const int lane = threadIdx.x & 63;
    const float inv = 1.0f / *gsum;
    const int start = offs[row], len = counts[row];
    const unsigned* vb32 = (const unsigned*)Vb;
    float ax = 0.f, ay = 0.f;
    for (int j = 0; j < len; ++j) {
        const int   c = bcol[start + j];
        const float w = bp[start + j] * inv;
        const unsigned u = vb32[(size_t)c * 64 + lane];
        ax += __uint_as_float(u << 16) * w;
        ay += __uint_as_float(u & 0xffff0000u) * w;
    }
    *(float2*)&out[(size_t)row * HDIM + lane * 2] = make_float2(ax, ay);
}

extern "C" void kernel_launch(void* const* d_in, const int* in_sizes, int n_in,
                              void* d_out, int out_size, void* d_ws, size_t ws_size,
                              hipStream_t stream)
{
    const float* x  = (const float*)d_in[0];
    const int*   ei = (const int*)d_in[1];
    const float* ew = (const float*)d_in[2];
    const float* Wq = (const float*)d_in[3];
    const float* bq = (const float*)d_in[4];
    const float* Wk = (const float*)d_in[5];
    const float* bk = (const float*)d_in[6];
    const float* Wv = (const float*)d_in[7];
    const float* bv = (const float*)d_in[8];
    float* out = (float*)d_out;

    float* ws = (float*)d_ws;
    float* Q       = ws;                                  // N*H fp32
    unsigned short* Kb = (unsigned short*)(Q + (size_t)N_NODES * HDIM);  // N*H bf16
    unsigned short* Vb = Kb + (size_t)N_NODES * HDIM;     // N*H bf16
    float* fp      = (float*)(Vb + (size_t)N_NODES * HDIM);
    int*   counts  = (int*)fp;                            // N
    int*   offs    = counts + N_NODES;                    // N
    int*   cursor  = offs + N_NODES;                      // N
    int*   aux     = cursor + N_NODES;                    // SCAN_BLOCKS
    int*   bcol    = aux + 256;                           // E
    float* bew     = (float*)(bcol + E_EDGES);            // E
    float* bp      = bew + E_EDGES;                       // E
    float* blockmax= bp + E_EDGES;                        // ROW_BLOCKS
    float* blocksum= blockmax + ROW_BLOCKS;               // EDGE_BLOCKS
    float* gmax    = blocksum + EDGE_BLOCKS;              // 1
    float* gsum    = gmax + 1;                            // 1
    float* WTq     = gsum + 1;                            // 128*128
    float* WTk     = WTq + HDIM * HDIM;                   // 128*128
    float* WTv     = WTk + HDIM * HDIM;                   // 128*128

    hipMemsetAsync(counts, 0, N_NODES * sizeof(int), stream);

    transpose_w_kernel<<<48, 256, 0, stream>>>(Wq, Wk, Wv, WTq, WTk, WTv);
    qkv_kernel<<<QKV_BLOCKS, 256, 0, stream>>>(x, WTq, bq, WTk, bk, WTv, bv, Q, Kb, Vb);
    hist_kernel<<<EDGE_BLOCKS, 256, 0, stream>>>(ei, counts);
    scan_partial_kernel<<<SCAN_BLOCKS, 256, 0, stream>>>(counts, offs, aux);
    scan_aux_kernel<<<1, 256, 0, stream>>>(aux);
    scan_add_kernel<<<SCAN_BLOCKS, 256, 0, stream>>>(offs, aux, cursor);
    bin_kernel<<<EDGE_BLOCKS, 256, 0, stream>>>(ei, ew, cursor, bcol, bew);
    energy_kernel<<<ROW_BLOCKS, 256, 0, stream>>>(Q, Kb, offs, counts, bcol, bew, bp, blockmax);
    reduce_max_kernel<<<1, 256, 0, stream>>>(blockmax, ROW_BLOCKS, gmax);
    expsum_kernel<<<EDGE_BLOCKS, 256, 0, stream>>>(bp, gmax, blocksum);
    reduce_sum_kernel<<<1, 256, 0, stream>>>(blocksum, EDGE_BLOCKS, gsum);
    accum_kernel<<<ROW_BLOCKS, 256, 0, stream>>>(Vb, offs, counts, bcol, bp, gsum, out);
}

// Round 9
// 245.111 us; speedup vs baseline: 2.1765x; 1.1501x over previous
//
#include <hip/hip_runtime.h>
#include <hip/hip_bf16.h>

#define N_NODES 50000
#define E_EDGES 600000
#define HDIM    128

#define QKV_BLOCKS  ((N_NODES + 63) / 64)     // 782 (64 rows/block, x3 mats in grid.y)
#define EDGE_BLOCKS ((E_EDGES + 255) / 256)   // 2344
#define SCAN_BLOCKS ((N_NODES + 255) / 256)   // 196
#define ROW_BLOCKS  (N_NODES / 4)             // 12500 (4 waves/block, 1 wave/row)

typedef float f32x4  __attribute__((ext_vector_type(4)));
typedef short short8 __attribute__((ext_vector_type(8)));

__device__ __forceinline__ unsigned short f2bf(float f) {
    __hip_bfloat16 h = __float2bfloat16(f);
    return *reinterpret_cast<unsigned short*>(&h);
}

// ---- Phase 1 (MFMA): Y = x W^T + b for W in {Wq,Wk,Wv} (blockIdx.y picks mat)
// Split precision: x = xh + xl, W = Wh + Wl (bf16); Y = xh*Wh + xl*Wh + xh*Wl.
// Block: 256 thr, 64 rows x 128 cols. Wave w owns cols 32w..32w+31 (2 strips).
// B-frags (hi/lo, full K=128) in registers, loaded straight from W (no transpose).
// A staged in LDS as bf16 hi/lo with XOR swizzle -> conflict-free ds_read_b128.
__global__ __launch_bounds__(256) void qkv_mfma_kernel(
    const float* __restrict__ x,
    const float* __restrict__ Wq, const float* __restrict__ bq,
    const float* __restrict__ Wk, const float* __restrict__ bk,
    const float* __restrict__ Wv, const float* __restrict__ bv,
    float* __restrict__ Q, unsigned short* __restrict__ Kb,
    unsigned short* __restrict__ Vb)
{
    __shared__ __align__(16) unsigned short Ah[64 * HDIM];  // 16 KB
    __shared__ __align__(16) unsigned short Al[64 * HDIM];  // 16 KB
    const int r0  = blockIdx.x * 64;
    const int mat = blockIdx.y;          // 0=Q 1=K 2=V

    // ---- stage x rows 64x128 as bf16 hi/lo, swizzled ----
    for (int t = threadIdx.x; t < 2048; t += 256) {
        const int r  = t >> 5;           // 0..63
        const int k4 = t & 31;           // float4 index 0..31
        int gr = r0 + r; if (gr >= N_NODES) gr = N_NODES - 1;
        const float4 xv = *(const float4*)&x[(size_t)gr * HDIM + k4 * 4];
        const unsigned ux = __float_as_uint(xv.x), uy = __float_as_uint(xv.y);
        const unsigned uz = __float_as_uint(xv.z), uw = __float_as_uint(xv.w);
        ushort4 hv, lv;
        hv.x = (unsigned short)(ux >> 16); hv.y = (unsigned short)(uy >> 16);
        hv.z = (unsigned short)(uz >> 16); hv.w = (unsigned short)(uw >> 16);
        lv.x = f2bf(xv.x - __uint_as_float(ux & 0xffff0000u));
        lv.y = f2bf(xv.y - __uint_as_float(uy & 0xffff0000u));
        lv.z = f2bf(xv.z - __uint_as_float(uz & 0xffff0000u));
        lv.w = f2bf(xv.w - __uint_as_float(uw & 0xffff0000u));
        const int byte = (r << 8) + (k4 << 3);
        const int swz  = byte ^ ((r & 7) << 4);
        *(ushort4*)((char*)Ah + swz) = hv;
        *(ushort4*)((char*)Al + swz) = lv;
    }

    const int lane = threadIdx.x & 63;
    const int w    = threadIdx.x >> 6;   // wave 0..3
    const int lrow = lane & 15;
    const int lgrp = lane >> 4;
    const int nb   = w * 32;             // wave's col base within mat

    const float* Wm = (mat == 0) ? Wq : (mat == 1) ? Wk : Wv;
    const float* bm = (mat == 0) ? bq : (mat == 1) ? bk : bv;

    // ---- B fragments: hi/lo, 2 strips x 4 k-steps ----
    short8 Bh[2][4], Bl[2][4];
#pragma unroll
    for (int st = 0; st < 2; ++st) {
        const int col = nb + st * 16 + lrow;
#pragma unroll
        for (int ks = 0; ks < 4; ++ks) {
            const int k0 = ks * 32 + lgrp * 8;
            const float* p = Wm + (size_t)col * HDIM + k0;
            const float4 a = *(const float4*)p;
            const float4 b = *(const float4*)(p + 4);
            const float f[8] = {a.x, a.y, a.z, a.w, b.x, b.y, b.z, b.w};
            short8 h, l;
#pragma unroll
            for (int j = 0; j < 8; ++j) {
                const unsigned u = __float_as_uint(f[j]);
                h[j] = (short)(u >> 16);
                l[j] = (short)f2bf(f[j] - __uint_as_float(u & 0xffff0000u));
            }
            Bh[st][ks] = h; Bl[st][ks] = l;
        }
    }
    const float bias0 = bm[nb + lrow];
    const float bias1 = bm[nb + 16 + lrow];

    __syncthreads();

    // ---- compute: 4 M-subtiles of 16 rows ----
#pragma unroll
    for (int s = 0; s < 4; ++s) {
        f32x4 acc0 = {0.f, 0.f, 0.f, 0.f};
        f32x4 acc1 = {0.f, 0.f, 0.f, 0.f};
        const int row = s * 16 + lrow;
#pragma unroll
        for (int ks = 0; ks < 4; ++ks) {
            const int byte = (row << 8) + ((ks * 32 + lgrp * 8) << 1);
            const int swz  = byte ^ ((row & 7) << 4);
            const short8 ah = *(const short8*)((const char*)Ah + swz);
            const short8 al = *(const short8*)((const char*)Al + swz);
            acc0 = __builtin_amdgcn_mfma_f32_16x16x32_bf16(ah, Bh[0][ks], acc0, 0, 0, 0);
            acc0 = __builtin_amdgcn_mfma_f32_16x16x32_bf16(al, Bh[0][ks], acc0, 0, 0, 0);
            acc0 = __builtin_amdgcn_mfma_f32_16x16x32_bf16(ah, Bl[0][ks], acc0, 0, 0, 0);
            acc1 = __builtin_amdgcn_mfma_f32_16x16x32_bf16(ah, Bh[1][ks], acc1, 0, 0, 0);
            acc1 = __builtin_amdgcn_mfma_f32_16x16x32_bf16(al, Bh[1][ks], acc1, 0, 0, 0);
            acc1 = __builtin_amdgcn_mfma_f32_16x16x32_bf16(ah, Bl[1][ks], acc1, 0, 0, 0);
        }
        const int orow0 = r0 + s * 16 + lgrp * 4;
        if (mat == 0) {
#pragma unroll
            for (int i = 0; i < 4; ++i) {
                const int row_o = orow0 + i;
                if (row_o < N_NODES) {
                    Q[(size_t)row_o * HDIM + nb + lrow]      = acc0[i] + bias0;
                    Q[(size_t)row_o * HDIM + nb + 16 + lrow] = acc1[i] + bias1;
                }
            }
        } else {
            unsigned short* dst = (mat == 1) ? Kb : Vb;
#pragma unroll
            for (int i = 0; i < 4; ++i) {
                const int row_o = orow0 + i;
                if (row_o < N_NODES) {
                    dst[(size_t)row_o * HDIM + nb + lrow]      = f2bf(acc0[i] + bias0);
                    dst[(size_t)row_o * HDIM + nb + 16 + lrow] = f2bf(acc1[i] + bias1);
                }
            }
        }
    }
}

// ---- Phase 2a: histogram of destination rows ----
__global__ __launch_bounds__(256) void hist_kernel(
    const int* __restrict__ ei, int* __restrict__ counts)
{
    const int e = blockIdx.x * 256 + threadIdx.x;
    if (e < E_EDGES) atomicAdd(&counts[ei[e]], 1);
}

// ---- Phase 2b: exclusive prefix scan (3 small kernels) ----
__global__ __launch_bounds__(256) void scan_partial_kernel(
    const int* __restrict__ counts, int* __restrict__ offs, int* __restrict__ aux)
{
    __shared__ int s[256];
    const int i = blockIdx.x * 256 + threadIdx.x;
    const int v = (i < N_NODES) ? counts[i] : 0;
    s[threadIdx.x] = v;
    __syncthreads();
    for (int d = 1; d < 256; d <<= 1) {
        int t = (threadIdx.x >= d) ? s[threadIdx.x - d] : 0;
        __syncthreads();
        s[threadIdx.x] += t;
        __syncthreads();
    }
    if (i < N_NODES) offs[i] = s[threadIdx.x] - v;   // exclusive within block
    if (threadIdx.x == 255) aux[blockIdx.x] = s[255];
}

__global__ __launch_bounds__(256) void scan_aux_kernel(int* __restrict__ aux)
{
    __shared__ int s[256];
    const int i = threadIdx.x;
    const int v = (i < SCAN_BLOCKS) ? aux[i] : 0;
    s[i] = v;
    __syncthreads();
    for (int d = 1; d < 256; d <<= 1) {
        int t = (i >= d) ? s[i - d] : 0;
        __syncthreads();
        s[i] += t;
        __syncthreads();
    }
    if (i < SCAN_BLOCKS) aux[i] = s[i] - v;          // exclusive
}

__global__ __launch_bounds__(256) void scan_add_kernel(
    int* __restrict__ offs, const int* __restrict__ aux, int* __restrict__ cursor)
{
    const int i = blockIdx.x * 256 + threadIdx.x;
    if (i < N_NODES) {
        const int o = offs[i] + aux[blockIdx.x];
        offs[i] = o;
        cursor[i] = o;
    }
}

// ---- Phase 2c: bin edges by destination row ----
__global__ __launch_bounds__(256) void bin_kernel(
    const int* __restrict__ ei, const float* __restrict__ ew,
    int* __restrict__ cursor, int* __restrict__ bcol, float* __restrict__ bew)
{
    const int e = blockIdx.x * 256 + threadIdx.x;
    if (e >= E_EDGES) return;
    const int row = ei[e];
    const int pos = atomicAdd(&cursor[row], 1);
    bcol[pos] = ei[E_EDGES + e];
    bew[pos]  = ew[e];
}

// ---- Phase 3: per-edge energy; 4 edges/wave, 16 lanes/edge ----
__global__ __launch_bounds__(256) void energy_kernel(
    const float* __restrict__ Q, const unsigned short* __restrict__ Kb,
    const int* __restrict__ offs, const int* __restrict__ counts,
    const int* __restrict__ bcol, const float* __restrict__ bew,
    float* __restrict__ bp, float* __restrict__ blockmax)
{
    const int row  = (blockIdx.x * 256 + threadIdx.x) >> 6;
    const int lane = threadIdx.x & 63;
    const int eg   = lane >> 4;     // edge group 0..3
    const int sl   = lane & 15;     // sub-lane in group
    const int start = offs[row], len = counts[row];
    const float4 q0 = *(const float4*)&Q[(size_t)row * HDIM + sl * 8];
    const float4 q1 = *(const float4*)&Q[(size_t)row * HDIM + sl * 8 + 4];
    const uint4* kb128 = (const uint4*)Kb;   // one row = 16 uint4
    const float inv_scale = 0.08838834764831845f;  // 1/sqrt(128)
    float lmax = -3.4e38f;
    for (int j0 = 0; j0 < len; j0 += 4) {
        const int  jj    = j0 + eg;
        const bool valid = jj < len;
        const int  e     = start + (valid ? jj : 0);
        const int  c     = bcol[e];
        const float w    = bew[e];
        const uint4 u = kb128[(size_t)c * 16 + sl];
        const float k0 = __uint_as_float(u.x << 16);
        const float k1 = __uint_as_float(u.x & 0xffff0000u);
        const float k2 = __uint_as_float(u.y << 16);
        const float k3 = __uint_as_float(u.y & 0xffff0000u);
        const float k4 = __uint_as_float(u.z << 16);
        const float k5 = __uint_as_float(u.z & 0xffff0000u);
        const float k6 = __uint_as_float(u.w << 16);
        const float k7 = __uint_as_float(u.w & 0xffff0000u);
        float d = q0.x * k0 + q0.y * k1 + q0.z * k2 + q0.w * k3
                + q1.x * k4 + q1.y * k5 + q1.z * k6 + q1.w * k7;
#pragma unroll
        for (int m = 8; m >= 1; m >>= 1) d += __shfl_xor(d, m);
        const float en = d * inv_scale * w;
        if (valid) {
            lmax = fmaxf(lmax, en);
            if (sl == 0) bp[e] = en;
        }
    }
#pragma unroll
    for (int m = 32; m >= 1; m >>= 1) lmax = fmaxf(lmax, __shfl_xor(lmax, m));
    __shared__ float sm[4];
    if (lane == 0) sm[threadIdx.x >> 6] = lmax;
    __syncthreads();
    if (threadIdx.x == 0)
        blockmax[blockIdx.x] = fmaxf(fmaxf(sm[0], sm[1]), fmaxf(sm[2], sm[3]));
}

__global__ __launch_bounds__(256) void reduce_max_kernel(
    const float* __restrict__ bm, int n, float* __restrict__ gmax)
{
    float m = -3.4e38f;
    for (int i = threadIdx.x; i < n; i += 256) m = fmaxf(m, bm[i]);
#pragma unroll
    for (int s = 32; s >= 1; s >>= 1) m = fmaxf(m, __shfl_xor(m, s));
    __shared__ float sm[4];
    if ((threadIdx.x & 63) == 0) sm[threadIdx.x >> 6] = m;
    __syncthreads();
    if (threadIdx.x == 0) *gmax = fmaxf(fmaxf(sm[0], sm[1]), fmaxf(sm[2], sm[3]));
}

// ---- Phase 4: p = exp(en - max), partial sums ----
__global__ __launch_bounds__(256) void expsum_kernel(
    float* __restrict__ bp, const float* __restrict__ gmax,
    float* __restrict__ blocksum)
{
    const float m = *gmax;
    const int e = blockIdx.x * 256 + threadIdx.x;
    float p = 0.f;
    if (e < E_EDGES) { p = __expf(bp[e] - m); bp[e] = p; }
#pragma unroll
    for (int s = 32; s >= 1; s >>= 1) p += __shfl_xor(p, s);
    __shared__ float sm[4];
    if ((threadIdx.x & 63) == 0) sm[threadIdx.x >> 6] = p;
    __syncthreads();
    if (threadIdx.x == 0) blocksum[blockIdx.x] = sm[0] + sm[1] + sm[2] + sm[3];
}

__global__ __launch_bounds__(256) void reduce_sum_kernel(
    const float* __restrict__ bs, int n, float* __restrict__ gsum)
{
    float v = 0.f;
    for (int i = threadIdx.x; i < n; i += 256) v += bs[i];
#pragma unroll
    for (int s = 32; s >= 1; s >>= 1) v += __shfl_xor(v, s);
    __shared__ float sm[4];
    if ((threadIdx.x & 63) == 0) sm[threadIdx.x >> 6] = v;
    __syncthreads();
    if (threadIdx.x == 0) *gsum = sm[0] + sm[1] + sm[2] + sm[3];
}

// ---- Phase 5: out[row] = sum_j V[bcol[j]] * p[j] / gsum; V gathered bf16 ----
__global__ __launch_bounds__(256) void accum_kernel(
    const unsigned short* __restrict__ Vb,
    const int* __restrict__ offs, const int* __restrict__ counts,
    const int* __restrict__ bcol, const float* __restrict__ bp,
    const float* __restrict__ gsum, float* __restrict__ out)
{
    const int row  = (blockIdx.x * 256 + threadIdx.x) >> 6;
    const int lane = threadIdx.x & 63;
    const float inv = 1.0f / *gsum;
    const int start = offs[row], len = counts[row];
    const unsigned* vb32 = (const unsigned*)Vb;
    float ax = 0.f, ay = 0.f;
    for (int j = 0; j < len; ++j) {
        const int   c = bcol[start + j];
        const float w = bp[start + j] * inv;
        const unsigned u = vb32[(size_t)c * 64 + lane];
        ax += __uint_as_float(u << 16) * w;
        ay += __uint_as_float(u & 0xffff0000u) * w;
    }
    *(float2*)&out[(size_t)row * HDIM + lane * 2] = make_float2(ax, ay);
}

extern "C" void kernel_launch(void* const* d_in, const int* in_sizes, int n_in,
                              void* d_out, int out_size, void* d_ws, size_t ws_size,
                              hipStream_t stream)
{
    const float* x  = (const float*)d_in[0];
    const int*   ei = (const int*)d_in[1];
    const float* ew = (const float*)d_in[2];
    const float* Wq = (const float*)d_in[3];
    const float* bq = (const float*)d_in[4];
    const float* Wk = (const float*)d_in[5];
    const float* bk = (const float*)d_in[6];
    const float* Wv = (const float*)d_in[7];
    const float* bv = (const float*)d_in[8];
    float* out = (float*)d_out;

    float* ws = (float*)d_ws;
    float* Q       = ws;                                  // N*H fp32
    unsigned short* Kb = (unsigned short*)(Q + (size_t)N_NODES * HDIM);  // N*H bf16
    unsigned short* Vb = Kb + (size_t)N_NODES * HDIM;     // N*H bf16
    float* fp      = (float*)(Vb + (size_t)N_NODES * HDIM);
    int*   counts  = (int*)fp;                            // N
    int*   offs    = counts + N_NODES;                    // N
    int*   cursor  = offs + N_NODES;                      // N
    int*   aux     = cursor + N_NODES;                    // SCAN_BLOCKS
    int*   bcol    = aux + 256;                           // E
    float* bew     = (float*)(bcol + E_EDGES);            // E
    float* bp      = bew + E_EDGES;                       // E
    float* blockmax= bp + E_EDGES;                        // ROW_BLOCKS
    float* blocksum= blockmax + ROW_BLOCKS;               // EDGE_BLOCKS
    float* gmax    = blocksum + EDGE_BLOCKS;              // 1
    float* gsum    = gmax + 1;                            // 1

    hipMemsetAsync(counts, 0, N_NODES * sizeof(int), stream);

    qkv_mfma_kernel<<<dim3(QKV_BLOCKS, 3), 256, 0, stream>>>(
        x, Wq, bq, Wk, bk, Wv, bv, Q, Kb, Vb);
    hist_kernel<<<EDGE_BLOCKS, 256, 0, stream>>>(ei, counts);
    scan_partial_kernel<<<SCAN_BLOCKS, 256, 0, stream>>>(counts, offs, aux);
    scan_aux_kernel<<<1, 256, 0, stream>>>(aux);
    scan_add_kernel<<<SCAN_BLOCKS, 256, 0, stream>>>(offs, aux, cursor);
    bin_kernel<<<EDGE_BLOCKS, 256, 0, stream>>>(ei, ew, cursor, bcol, bew);
    energy_kernel<<<ROW_BLOCKS, 256, 0, stream>>>(Q, Kb, offs, counts, bcol, bew, bp, blockmax);
    reduce_max_kernel<<<1, 256, 0, stream>>>(blockmax, ROW_BLOCKS, gmax);
    expsum_kernel<<<EDGE_BLOCKS, 256, 0, stream>>>(bp, gmax, blocksum);
    reduce_sum_kernel<<<1, 256, 0, stream>>>(blocksum, EDGE_BLOCKS, gsum);
    accum_kernel<<<ROW_BLOCKS, 256, 0, stream>>>(Vb, offs, counts, bcol, bp, gsum, out);
}

// Round 10
// 212.378 us; speedup vs baseline: 2.5119x; 1.1541x over previous
//
#include <hip/hip_runtime.h>
#include <hip/hip_bf16.h>

#define N_NODES 50000
#define E_EDGES 600000
#define HDIM    128

#define QKV_BLOCKS  ((N_NODES + 63) / 64)     // 782 (64 rows/block, x3 mats in grid.y)
#define EDGE_BLOCKS ((E_EDGES + 255) / 256)   // 2344
#define SCAN_BLOCKS ((N_NODES + 255) / 256)   // 196
#define ROW_BLOCKS  (N_NODES / 4)             // 12500 (4 waves/block, 1 wave/row)

typedef float f32x4  __attribute__((ext_vector_type(4)));
typedef short short8 __attribute__((ext_vector_type(8)));

__device__ __forceinline__ unsigned short f2bf(float f) {
    __hip_bfloat16 h = __float2bfloat16(f);
    return *reinterpret_cast<unsigned short*>(&h);
}

// ---- Phase 1 (MFMA): Y = x W^T + b for W in {Wq,Wk,Wv} (blockIdx.y picks mat)
// Split precision: x = xh + xl, W = Wh + Wl (bf16); Y = xh*Wh + xl*Wh + xh*Wl.
__global__ __launch_bounds__(256) void qkv_mfma_kernel(
    const float* __restrict__ x,
    const float* __restrict__ Wq, const float* __restrict__ bq,
    const float* __restrict__ Wk, const float* __restrict__ bk,
    const float* __restrict__ Wv, const float* __restrict__ bv,
    float* __restrict__ Q, unsigned short* __restrict__ Kb,
    unsigned short* __restrict__ Vb)
{
    __shared__ __align__(16) unsigned short Ah[64 * HDIM];  // 16 KB
    __shared__ __align__(16) unsigned short Al[64 * HDIM];  // 16 KB
    const int r0  = blockIdx.x * 64;
    const int mat = blockIdx.y;          // 0=Q 1=K 2=V

    // ---- stage x rows 64x128 as bf16 hi/lo, swizzled ----
    for (int t = threadIdx.x; t < 2048; t += 256) {
        const int r  = t >> 5;           // 0..63
        const int k4 = t & 31;           // float4 index 0..31
        int gr = r0 + r; if (gr >= N_NODES) gr = N_NODES - 1;
        const float4 xv = *(const float4*)&x[(size_t)gr * HDIM + k4 * 4];
        const unsigned ux = __float_as_uint(xv.x), uy = __float_as_uint(xv.y);
        const unsigned uz = __float_as_uint(xv.z), uw = __float_as_uint(xv.w);
        ushort4 hv, lv;
        hv.x = (unsigned short)(ux >> 16); hv.y = (unsigned short)(uy >> 16);
        hv.z = (unsigned short)(uz >> 16); hv.w = (unsigned short)(uw >> 16);
        lv.x = f2bf(xv.x - __uint_as_float(ux & 0xffff0000u));
        lv.y = f2bf(xv.y - __uint_as_float(uy & 0xffff0000u));
        lv.z = f2bf(xv.z - __uint_as_float(uz & 0xffff0000u));
        lv.w = f2bf(xv.w - __uint_as_float(uw & 0xffff0000u));
        const int byte = (r << 8) + (k4 << 3);
        const int swz  = byte ^ ((r & 7) << 4);
        *(ushort4*)((char*)Ah + swz) = hv;
        *(ushort4*)((char*)Al + swz) = lv;
    }

    const int lane = threadIdx.x & 63;
    const int w    = threadIdx.x >> 6;   // wave 0..3
    const int lrow = lane & 15;
    const int lgrp = lane >> 4;
    const int nb   = w * 32;             // wave's col base within mat

    const float* Wm = (mat == 0) ? Wq : (mat == 1) ? Wk : Wv;
    const float* bm = (mat == 0) ? bq : (mat == 1) ? bk : bv;

    // ---- B fragments: hi/lo, 2 strips x 4 k-steps ----
    short8 Bh[2][4], Bl[2][4];
#pragma unroll
    for (int st = 0; st < 2; ++st) {
        const int col = nb + st * 16 + lrow;
#pragma unroll
        for (int ks = 0; ks < 4; ++ks) {
            const int k0 = ks * 32 + lgrp * 8;
            const float* p = Wm + (size_t)col * HDIM + k0;
            const float4 a = *(const float4*)p;
            const float4 b = *(const float4*)(p + 4);
            const float f[8] = {a.x, a.y, a.z, a.w, b.x, b.y, b.z, b.w};
            short8 h, l;
#pragma unroll
            for (int j = 0; j < 8; ++j) {
                const unsigned u = __float_as_uint(f[j]);
                h[j] = (short)(u >> 16);
                l[j] = (short)f2bf(f[j] - __uint_as_float(u & 0xffff0000u));
            }
            Bh[st][ks] = h; Bl[st][ks] = l;
        }
    }
    const float bias0 = bm[nb + lrow];
    const float bias1 = bm[nb + 16 + lrow];

    __syncthreads();

    // ---- compute: 4 M-subtiles of 16 rows ----
#pragma unroll
    for (int s = 0; s < 4; ++s) {
        f32x4 acc0 = {0.f, 0.f, 0.f, 0.f};
        f32x4 acc1 = {0.f, 0.f, 0.f, 0.f};
        const int row = s * 16 + lrow;
#pragma unroll
        for (int ks = 0; ks < 4; ++ks) {
            const int byte = (row << 8) + ((ks * 32 + lgrp * 8) << 1);
            const int swz  = byte ^ ((row & 7) << 4);
            const short8 ah = *(const short8*)((const char*)Ah + swz);
            const short8 al = *(const short8*)((const char*)Al + swz);
            acc0 = __builtin_amdgcn_mfma_f32_16x16x32_bf16(ah, Bh[0][ks], acc0, 0, 0, 0);
            acc0 = __builtin_amdgcn_mfma_f32_16x16x32_bf16(al, Bh[0][ks], acc0, 0, 0, 0);
            acc0 = __builtin_amdgcn_mfma_f32_16x16x32_bf16(ah, Bl[0][ks], acc0, 0, 0, 0);
            acc1 = __builtin_amdgcn_mfma_f32_16x16x32_bf16(ah, Bh[1][ks], acc1, 0, 0, 0);
            acc1 = __builtin_amdgcn_mfma_f32_16x16x32_bf16(al, Bh[1][ks], acc1, 0, 0, 0);
            acc1 = __builtin_amdgcn_mfma_f32_16x16x32_bf16(ah, Bl[1][ks], acc1, 0, 0, 0);
        }
        const int orow0 = r0 + s * 16 + lgrp * 4;
        if (mat == 0) {
#pragma unroll
            for (int i = 0; i < 4; ++i) {
                const int row_o = orow0 + i;
                if (row_o < N_NODES) {
                    Q[(size_t)row_o * HDIM + nb + lrow]      = acc0[i] + bias0;
                    Q[(size_t)row_o * HDIM + nb + 16 + lrow] = acc1[i] + bias1;
                }
            }
        } else {
            unsigned short* dst = (mat == 1) ? Kb : Vb;
#pragma unroll
            for (int i = 0; i < 4; ++i) {
                const int row_o = orow0 + i;
                if (row_o < N_NODES) {
                    dst[(size_t)row_o * HDIM + nb + lrow]      = f2bf(acc0[i] + bias0);
                    dst[(size_t)row_o * HDIM + nb + 16 + lrow] = f2bf(acc1[i] + bias1);
                }
            }
        }
    }
}

// ---- Phase 2a: histogram of destination rows ----
__global__ __launch_bounds__(256) void hist_kernel(
    const int* __restrict__ ei, int* __restrict__ counts)
{
    const int e = blockIdx.x * 256 + threadIdx.x;
    if (e < E_EDGES) atomicAdd(&counts[ei[e]], 1);
}

// ---- Phase 2b: exclusive prefix scan (3 small kernels) ----
__global__ __launch_bounds__(256) void scan_partial_kernel(
    const int* __restrict__ counts, int* __restrict__ offs, int* __restrict__ aux)
{
    __shared__ int s[256];
    const int i = blockIdx.x * 256 + threadIdx.x;
    const int v = (i < N_NODES) ? counts[i] : 0;
    s[threadIdx.x] = v;
    __syncthreads();
    for (int d = 1; d < 256; d <<= 1) {
        int t = (threadIdx.x >= d) ? s[threadIdx.x - d] : 0;
        __syncthreads();
        s[threadIdx.x] += t;
        __syncthreads();
    }
    if (i < N_NODES) offs[i] = s[threadIdx.x] - v;   // exclusive within block
    if (threadIdx.x == 255) aux[blockIdx.x] = s[255];
}

__global__ __launch_bounds__(256) void scan_aux_kernel(int* __restrict__ aux)
{
    __shared__ int s[256];
    const int i = threadIdx.x;
    const int v = (i < SCAN_BLOCKS) ? aux[i] : 0;
    s[i] = v;
    __syncthreads();
    for (int d = 1; d < 256; d <<= 1) {
        int t = (i >= d) ? s[i - d] : 0;
        __syncthreads();
        s[i] += t;
        __syncthreads();
    }
    if (i < SCAN_BLOCKS) aux[i] = s[i] - v;          // exclusive
}

__global__ __launch_bounds__(256) void scan_add_kernel(
    int* __restrict__ offs, const int* __restrict__ aux, int* __restrict__ cursor)
{
    const int i = blockIdx.x * 256 + threadIdx.x;
    if (i < N_NODES) {
        const int o = offs[i] + aux[blockIdx.x];
        offs[i] = o;
        cursor[i] = o;
    }
}

// ---- Phase 2c: bin edges by destination row ----
__global__ __launch_bounds__(256) void bin_kernel(
    const int* __restrict__ ei, const float* __restrict__ ew,
    int* __restrict__ cursor, int* __restrict__ bcol, float* __restrict__ bew)
{
    const int e = blockIdx.x * 256 + threadIdx.x;
    if (e >= E_EDGES) return;
    const int row = ei[e];
    const int pos = atomicAdd(&cursor[row], 1);
    bcol[pos] = ei[E_EDGES + e];
    bew[pos]  = ew[e];
}

// ---- Phase 3: per-edge energy; 4 edges/wave, 16 lanes/edge ----
__global__ __launch_bounds__(256) void energy_kernel(
    const float* __restrict__ Q, const unsigned short* __restrict__ Kb,
    const int* __restrict__ offs, const int* __restrict__ counts,
    const int* __restrict__ bcol, const float* __restrict__ bew,
    float* __restrict__ bp, float* __restrict__ blockmax)
{
    const int row  = (blockIdx.x * 256 + threadIdx.x) >> 6;
    const int lane = threadIdx.x & 63;
    const int eg   = lane >> 4;     // edge group 0..3
    const int sl   = lane & 15;     // sub-lane in group
    const int start = offs[row], len = counts[row];
    const float4 q0 = *(const float4*)&Q[(size_t)row * HDIM + sl * 8];
    const float4 q1 = *(const float4*)&Q[(size_t)row * HDIM + sl * 8 + 4];
    const uint4* kb128 = (const uint4*)Kb;   // one row = 16 uint4
    const float inv_scale = 0.08838834764831845f;  // 1/sqrt(128)
    float lmax = -3.4e38f;
    for (int j0 = 0; j0 < len; j0 += 4) {
        const int  jj    = j0 + eg;
        const bool valid = jj < len;
        const int  e     = start + (valid ? jj : 0);
        const int  c     = bcol[e];
        const float w    = bew[e];
        const uint4 u = kb128[(size_t)c * 16 + sl];
        const float k0 = __uint_as_float(u.x << 16);
        const float k1 = __uint_as_float(u.x & 0xffff0000u);
        const float k2 = __uint_as_float(u.y << 16);
        const float k3 = __uint_as_float(u.y & 0xffff0000u);
        const float k4 = __uint_as_float(u.z << 16);
        const float k5 = __uint_as_float(u.z & 0xffff0000u);
        const float k6 = __uint_as_float(u.w << 16);
        const float k7 = __uint_as_float(u.w & 0xffff0000u);
        float d = q0.x * k0 + q0.y * k1 + q0.z * k2 + q0.w * k3
                + q1.x * k4 + q1.y * k5 + q1.z * k6 + q1.w * k7;
#pragma unroll
        for (int m = 8; m >= 1; m >>= 1) d += __shfl_xor(d, m);
        const float en = d * inv_scale * w;
        if (valid) {
            lmax = fmaxf(lmax, en);
            if (sl == 0) bp[e] = en;
        }
    }
#pragma unroll
    for (int m = 32; m >= 1; m >>= 1) lmax = fmaxf(lmax, __shfl_xor(lmax, m));
    __shared__ float sm[4];
    if (lane == 0) sm[threadIdx.x >> 6] = lmax;
    __syncthreads();
    if (threadIdx.x == 0)
        blockmax[blockIdx.x] = fmaxf(fmaxf(sm[0], sm[1]), fmaxf(sm[2], sm[3]));
}

__global__ __launch_bounds__(256) void reduce_max_kernel(
    const float* __restrict__ bm, int n, float* __restrict__ gmax)
{
    float m = -3.4e38f;
    for (int i = threadIdx.x; i < n; i += 256) m = fmaxf(m, bm[i]);
#pragma unroll
    for (int s = 32; s >= 1; s >>= 1) m = fmaxf(m, __shfl_xor(m, s));
    __shared__ float sm[4];
    if ((threadIdx.x & 63) == 0) sm[threadIdx.x >> 6] = m;
    __syncthreads();
    if (threadIdx.x == 0) *gmax = fmaxf(fmaxf(sm[0], sm[1]), fmaxf(sm[2], sm[3]));
}

// ---- Phase 4: p = exp(en - max), partial sums ----
__global__ __launch_bounds__(256) void expsum_kernel(
    float* __restrict__ bp, const float* __restrict__ gmax,
    float* __restrict__ blocksum)
{
    const float m = *gmax;
    const int e = blockIdx.x * 256 + threadIdx.x;
    float p = 0.f;
    if (e < E_EDGES) { p = __expf(bp[e] - m); bp[e] = p; }
#pragma unroll
    for (int s = 32; s >= 1; s >>= 1) p += __shfl_xor(p, s);
    __shared__ float sm[4];
    if ((threadIdx.x & 63) == 0) sm[threadIdx.x >> 6] = p;
    __syncthreads();
    if (threadIdx.x == 0) blocksum[blockIdx.x] = sm[0] + sm[1] + sm[2] + sm[3];
}

__global__ __launch_bounds__(256) void reduce_sum_kernel(
    const float* __restrict__ bs, int n, float* __restrict__ gsum)
{
    float v = 0.f;
    for (int i = threadIdx.x; i < n; i += 256) v += bs[i];
#pragma unroll
    for (int s = 32; s >= 1; s >>= 1) v += __shfl_xor(v, s);
    __shared__ float sm[4];
    if ((threadIdx.x & 63) == 0) sm[threadIdx.x >> 6] = v;
    __syncthreads();
    if (threadIdx.x == 0) *gsum = sm[0] + sm[1] + sm[2] + sm[3];
}

// ---- Phase 5: out[row] = sum_j V[bcol[j]] * p[j] / gsum ----
// 4 edges/wave, 16 lanes/edge: lane accumulates 8 dims (uint4 of bf16 V);
// 4 row-gathers in flight; cross-group fold via 2 shfl_xor at row end.
__global__ __launch_bounds__(256) void accum_kernel(
    const unsigned short* __restrict__ Vb,
    const int* __restrict__ offs, const int* __restrict__ counts,
    const int* __restrict__ bcol, const float* __restrict__ bp,
    const float* __restrict__ gsum, float* __restrict__ out)
{
    const int row  = (blockIdx.x * 256 + threadIdx.x) >> 6;
    const int lane = threadIdx.x & 63;
    const int eg   = lane >> 4;     // edge group 0..3
    const int sl   = lane & 15;     // sub-lane: dims sl*8..sl*8+7
    const float inv = 1.0f / *gsum;
    const int start = offs[row], len = counts[row];
    const uint4* vb128 = (const uint4*)Vb;   // one row = 16 uint4
    float a0 = 0.f, a1 = 0.f, a2 = 0.f, a3 = 0.f;
    float a4 = 0.f, a5 = 0.f, a6 = 0.f, a7 = 0.f;
    for (int j0 = 0; j0 < len; j0 += 4) {
        const int  jj    = j0 + eg;
        const bool valid = jj < len;
        const int  e     = start + (valid ? jj : 0);
        const int  c     = bcol[e];
        const float w    = valid ? bp[e] * inv : 0.f;
        const uint4 u = vb128[(size_t)c * 16 + sl];
        a0 += __uint_as_float(u.x << 16) * w;
        a1 += __uint_as_float(u.x & 0xffff0000u) * w;
        a2 += __uint_as_float(u.y << 16) * w;
        a3 += __uint_as_float(u.y & 0xffff0000u) * w;
        a4 += __uint_as_float(u.z << 16) * w;
        a5 += __uint_as_float(u.z & 0xffff0000u) * w;
        a6 += __uint_as_float(u.w << 16) * w;
        a7 += __uint_as_float(u.w & 0xffff0000u) * w;
    }
    // fold the 4 edge groups (lanes sl, sl+16, sl+32, sl+48)
    a0 += __shfl_xor(a0, 16); a0 += __shfl_xor(a0, 32);
    a1 += __shfl_xor(a1, 16); a1 += __shfl_xor(a1, 32);
    a2 += __shfl_xor(a2, 16); a2 += __shfl_xor(a2, 32);
    a3 += __shfl_xor(a3, 16); a3 += __shfl_xor(a3, 32);
    a4 += __shfl_xor(a4, 16); a4 += __shfl_xor(a4, 32);
    a5 += __shfl_xor(a5, 16); a5 += __shfl_xor(a5, 32);
    a6 += __shfl_xor(a6, 16); a6 += __shfl_xor(a6, 32);
    a7 += __shfl_xor(a7, 16); a7 += __shfl_xor(a7, 32);
    if (eg == 0) {
        float* o = out + (size_t)row * HDIM + sl * 8;
        *(float4*)o       = make_float4(a0, a1, a2, a3);
        *(float4*)(o + 4) = make_float4(a4, a5, a6, a7);
    }
}

extern "C" void kernel_launch(void* const* d_in, const int* in_sizes, int n_in,
                              void* d_out, int out_size, void* d_ws, size_t ws_size,
                              hipStream_t stream)
{
    const float* x  = (const float*)d_in[0];
    const int*   ei = (const int*)d_in[1];
    const float* ew = (const float*)d_in[2];
    const float* Wq = (const float*)d_in[3];
    const float* bq = (const float*)d_in[4];
    const float* Wk = (const float*)d_in[5];
    const float* bk = (const float*)d_in[6];
    const float* Wv = (const float*)d_in[7];
    const float* bv = (const float*)d_in[8];
    float* out = (float*)d_out;

    float* ws = (float*)d_ws;
    float* Q       = ws;                                  // N*H fp32
    unsigned short* Kb = (unsigned short*)(Q + (size_t)N_NODES * HDIM);  // N*H bf16
    unsigned short* Vb = Kb + (size_t)N_NODES * HDIM;     // N*H bf16
    float* fp      = (float*)(Vb + (size_t)N_NODES * HDIM);
    int*   counts  = (int*)fp;                            // N
    int*   offs    = counts + N_NODES;                    // N
    int*   cursor  = offs + N_NODES;                      // N
    int*   aux     = cursor + N_NODES;                    // SCAN_BLOCKS
    int*   bcol    = aux + 256;                           // E
    float* bew     = (float*)(bcol + E_EDGES);            // E
    float* bp      = bew + E_EDGES;                       // E
    float* blockmax= bp + E_EDGES;                        // ROW_BLOCKS
    float* blocksum= blockmax + ROW_BLOCKS;               // EDGE_BLOCKS
    float* gmax    = blocksum + EDGE_BLOCKS;              // 1
    float* gsum    = gmax + 1;                            // 1

    hipMemsetAsync(counts, 0, N_NODES * sizeof(int), stream);

    qkv_mfma_kernel<<<dim3(QKV_BLOCKS, 3), 256, 0, stream>>>(
        x, Wq, bq, Wk, bk, Wv, bv, Q, Kb, Vb);
    hist_kernel<<<EDGE_BLOCKS, 256, 0, stream>>>(ei, counts);
    scan_partial_kernel<<<SCAN_BLOCKS, 256, 0, stream>>>(counts, offs, aux);
    scan_aux_kernel<<<1, 256, 0, stream>>>(aux);
    scan_add_kernel<<<SCAN_BLOCKS, 256, 0, stream>>>(offs, aux, cursor);
    bin_kernel<<<EDGE_BLOCKS, 256, 0, stream>>>(ei, ew, cursor, bcol, bew);
    energy_kernel<<<ROW_BLOCKS, 256, 0, stream>>>(Q, Kb, offs, counts, bcol, bew, bp, blockmax);
    reduce_max_kernel<<<1, 256, 0, stream>>>(blockmax, ROW_BLOCKS, gmax);
    expsum_kernel<<<EDGE_BLOCKS, 256, 0, stream>>>(bp, gmax, blocksum);
    reduce_sum_kernel<<<1, 256, 0, stream>>>(blocksum, EDGE_BLOCKS, gsum);
    accum_kernel<<<ROW_BLOCKS, 256, 0, stream>>>(Vb, offs, counts, bcol, bp, gsum, out);
}

// Round 11
// 186.512 us; speedup vs baseline: 2.8603x; 1.1387x over previous
//
#include <hip/hip_runtime.h>
#include <hip/hip_bf16.h>

#define N_NODES 50000
#define E_EDGES 600000
#define HDIM    128

#define QKV_BLOCKS  ((N_NODES + 63) / 64)     // 782 (64 rows/block, x3 mats in grid.y)
#define EDGE_BLOCKS ((E_EDGES + 255) / 256)   // 2344
#define SCAN_BLOCKS ((N_NODES + 255) / 256)   // 196
#define ROW_BLOCKS  (N_NODES / 4)             // 12500 (4 waves/block, 1 wave/row)

typedef float f32x4  __attribute__((ext_vector_type(4)));
typedef short short8 __attribute__((ext_vector_type(8)));

__device__ __forceinline__ unsigned short f2bf(float f) {
    __hip_bfloat16 h = __float2bfloat16(f);
    return *reinterpret_cast<unsigned short*>(&h);
}

// ---- Phase 1 (MFMA): Y = x W^T + b for W in {Wq,Wk,Wv} (blockIdx.y picks mat)
// Split precision: x = xh + xl, W = Wh + Wl (bf16); Y = xh*Wh + xl*Wh + xh*Wl.
__global__ __launch_bounds__(256) void qkv_mfma_kernel(
    const float* __restrict__ x,
    const float* __restrict__ Wq, const float* __restrict__ bq,
    const float* __restrict__ Wk, const float* __restrict__ bk,
    const float* __restrict__ Wv, const float* __restrict__ bv,
    float* __restrict__ Q, unsigned short* __restrict__ Kb,
    unsigned short* __restrict__ Vb)
{
    __shared__ __align__(16) unsigned short Ah[64 * HDIM];  // 16 KB
    __shared__ __align__(16) unsigned short Al[64 * HDIM];  // 16 KB
    const int r0  = blockIdx.x * 64;
    const int mat = blockIdx.y;          // 0=Q 1=K 2=V

    // ---- stage x rows 64x128 as bf16 hi/lo, swizzled ----
    for (int t = threadIdx.x; t < 2048; t += 256) {
        const int r  = t >> 5;           // 0..63
        const int k4 = t & 31;           // float4 index 0..31
        int gr = r0 + r; if (gr >= N_NODES) gr = N_NODES - 1;
        const float4 xv = *(const float4*)&x[(size_t)gr * HDIM + k4 * 4];
        const unsigned ux = __float_as_uint(xv.x), uy = __float_as_uint(xv.y);
        const unsigned uz = __float_as_uint(xv.z), uw = __float_as_uint(xv.w);
        ushort4 hv, lv;
        hv.x = (unsigned short)(ux >> 16); hv.y = (unsigned short)(uy >> 16);
        hv.z = (unsigned short)(uz >> 16); hv.w = (unsigned short)(uw >> 16);
        lv.x = f2bf(xv.x - __uint_as_float(ux & 0xffff0000u));
        lv.y = f2bf(xv.y - __uint_as_float(uy & 0xffff0000u));
        lv.z = f2bf(xv.z - __uint_as_float(uz & 0xffff0000u));
        lv.w = f2bf(xv.w - __uint_as_float(uw & 0xffff0000u));
        const int byte = (r << 8) + (k4 << 3);
        const int swz  = byte ^ ((r & 7) << 4);
        *(ushort4*)((char*)Ah + swz) = hv;
        *(ushort4*)((char*)Al + swz) = lv;
    }

    const int lane = threadIdx.x & 63;
    const int w    = threadIdx.x >> 6;   // wave 0..3
    const int lrow = lane & 15;
    const int lgrp = lane >> 4;
    const int nb   = w * 32;             // wave's col base within mat

    const float* Wm = (mat == 0) ? Wq : (mat == 1) ? Wk : Wv;
    const float* bm = (mat == 0) ? bq : (mat == 1) ? bk : bv;

    // ---- B fragments: hi/lo, 2 strips x 4 k-steps ----
    short8 Bh[2][4], Bl[2][4];
#pragma unroll
    for (int st = 0; st < 2; ++st) {
        const int col = nb + st * 16 + lrow;
#pragma unroll
        for (int ks = 0; ks < 4; ++ks) {
            const int k0 = ks * 32 + lgrp * 8;
            const float* p = Wm + (size_t)col * HDIM + k0;
            const float4 a = *(const float4*)p;
            const float4 b = *(const float4*)(p + 4);
            const float f[8] = {a.x, a.y, a.z, a.w, b.x, b.y, b.z, b.w};
            short8 h, l;
#pragma unroll
            for (int j = 0; j < 8; ++j) {
                const unsigned u = __float_as_uint(f[j]);
                h[j] = (short)(u >> 16);
                l[j] = (short)f2bf(f[j] - __uint_as_float(u & 0xffff0000u));
            }
            Bh[st][ks] = h; Bl[st][ks] = l;
        }
    }
    const float bias0 = bm[nb + lrow];
    const float bias1 = bm[nb + 16 + lrow];

    __syncthreads();

    // ---- compute: 4 M-subtiles of 16 rows ----
#pragma unroll
    for (int s = 0; s < 4; ++s) {
        f32x4 acc0 = {0.f, 0.f, 0.f, 0.f};
        f32x4 acc1 = {0.f, 0.f, 0.f, 0.f};
        const int row = s * 16 + lrow;
#pragma unroll
        for (int ks = 0; ks < 4; ++ks) {
            const int byte = (row << 8) + ((ks * 32 + lgrp * 8) << 1);
            const int swz  = byte ^ ((row & 7) << 4);
            const short8 ah = *(const short8*)((const char*)Ah + swz);
            const short8 al = *(const short8*)((const char*)Al + swz);
            acc0 = __builtin_amdgcn_mfma_f32_16x16x32_bf16(ah, Bh[0][ks], acc0, 0, 0, 0);
            acc0 = __builtin_amdgcn_mfma_f32_16x16x32_bf16(al, Bh[0][ks], acc0, 0, 0, 0);
            acc0 = __builtin_amdgcn_mfma_f32_16x16x32_bf16(ah, Bl[0][ks], acc0, 0, 0, 0);
            acc1 = __builtin_amdgcn_mfma_f32_16x16x32_bf16(ah, Bh[1][ks], acc1, 0, 0, 0);
            acc1 = __builtin_amdgcn_mfma_f32_16x16x32_bf16(al, Bh[1][ks], acc1, 0, 0, 0);
            acc1 = __builtin_amdgcn_mfma_f32_16x16x32_bf16(ah, Bl[1][ks], acc1, 0, 0, 0);
        }
        const int orow0 = r0 + s * 16 + lgrp * 4;
        if (mat == 0) {
#pragma unroll
            for (int i = 0; i < 4; ++i) {
                const int row_o = orow0 + i;
                if (row_o < N_NODES) {
                    Q[(size_t)row_o * HDIM + nb + lrow]      = acc0[i] + bias0;
                    Q[(size_t)row_o * HDIM + nb + 16 + lrow] = acc1[i] + bias1;
                }
            }
        } else {
            unsigned short* dst = (mat == 1) ? Kb : Vb;
#pragma unroll
            for (int i = 0; i < 4; ++i) {
                const int row_o = orow0 + i;
                if (row_o < N_NODES) {
                    dst[(size_t)row_o * HDIM + nb + lrow]      = f2bf(acc0[i] + bias0);
                    dst[(size_t)row_o * HDIM + nb + 16 + lrow] = f2bf(acc1[i] + bias1);
                }
            }
        }
    }
}

// ---- Phase 2a: histogram of destination rows ----
__global__ __launch_bounds__(256) void hist_kernel(
    const int* __restrict__ ei, int* __restrict__ counts)
{
    const int e = blockIdx.x * 256 + threadIdx.x;
    if (e < E_EDGES) atomicAdd(&counts[ei[e]], 1);
}

// ---- Phase 2b: exclusive prefix scan (3 small kernels) ----
__global__ __launch_bounds__(256) void scan_partial_kernel(
    const int* __restrict__ counts, int* __restrict__ offs, int* __restrict__ aux)
{
    __shared__ int s[256];
    const int i = blockIdx.x * 256 + threadIdx.x;
    const int v = (i < N_NODES) ? counts[i] : 0;
    s[threadIdx.x] = v;
    __syncthreads();
    for (int d = 1; d < 256; d <<= 1) {
        int t = (threadIdx.x >= d) ? s[threadIdx.x - d] : 0;
        __syncthreads();
        s[threadIdx.x] += t;
        __syncthreads();
    }
    if (i < N_NODES) offs[i] = s[threadIdx.x] - v;   // exclusive within block
    if (threadIdx.x == 255) aux[blockIdx.x] = s[255];
}

__global__ __launch_bounds__(256) void scan_aux_kernel(int* __restrict__ aux)
{
    __shared__ int s[256];
    const int i = threadIdx.x;
    const int v = (i < SCAN_BLOCKS) ? aux[i] : 0;
    s[i] = v;
    __syncthreads();
    for (int d = 1; d < 256; d <<= 1) {
        int t = (i >= d) ? s[i - d] : 0;
        __syncthreads();
        s[i] += t;
        __syncthreads();
    }
    if (i < SCAN_BLOCKS) aux[i] = s[i] - v;          // exclusive
}

__global__ __launch_bounds__(256) void scan_add_kernel(
    int* __restrict__ offs, const int* __restrict__ aux, int* __restrict__ cursor)
{
    const int i = blockIdx.x * 256 + threadIdx.x;
    if (i < N_NODES) {
        const int o = offs[i] + aux[blockIdx.x];
        offs[i] = o;
        cursor[i] = o;
    }
}

// ---- Phase 2c: bin edges by destination row; ONE 8B record per edge ----
__global__ __launch_bounds__(256) void bin_kernel(
    const int* __restrict__ ei, const float* __restrict__ ew,
    int* __restrict__ cursor, uint2* __restrict__ erec)
{
    const int e = blockIdx.x * 256 + threadIdx.x;
    if (e >= E_EDGES) return;
    const int row = ei[e];
    const int pos = atomicAdd(&cursor[row], 1);
    erec[pos] = make_uint2((unsigned)ei[E_EDGES + e], __float_as_uint(ew[e]));
}

// ---- Phase 3: energy; 8 edges/wave in flight (2x unroll of 4 groups) ----
__global__ __launch_bounds__(256) void energy_kernel(
    const float* __restrict__ Q, const unsigned short* __restrict__ Kb,
    const int* __restrict__ offs, const int* __restrict__ counts,
    uint2* __restrict__ erec, float* __restrict__ blockmax)
{
    const int row  = (blockIdx.x * 256 + threadIdx.x) >> 6;
    const int lane = threadIdx.x & 63;
    const int eg   = lane >> 4;     // edge group 0..3
    const int sl   = lane & 15;     // sub-lane in group
    const int start = offs[row], len = counts[row];
    const float4 q0 = *(const float4*)&Q[(size_t)row * HDIM + sl * 8];
    const float4 q1 = *(const float4*)&Q[(size_t)row * HDIM + sl * 8 + 4];
    const uint4* kb128 = (const uint4*)Kb;   // one row = 16 uint4
    const float inv_scale = 0.08838834764831845f;  // 1/sqrt(128)
    float lmax = -3.4e38f;
    for (int j0 = 0; j0 < len; j0 += 8) {
        const int  jA = j0 + eg,      jB = j0 + 4 + eg;
        const bool vA = jA < len,     vB = jB < len;
        const int  eA = start + (vA ? jA : 0);
        const int  eB = start + (vB ? jB : 0);
        const uint2 rA = erec[eA];
        const uint2 rB = erec[eB];
        const uint4 uA = kb128[(size_t)rA.x * 16 + sl];
        const uint4 uB = kb128[(size_t)rB.x * 16 + sl];
        float dA = q0.x * __uint_as_float(uA.x << 16)
                 + q0.y * __uint_as_float(uA.x & 0xffff0000u)
                 + q0.z * __uint_as_float(uA.y << 16)
                 + q0.w * __uint_as_float(uA.y & 0xffff0000u)
                 + q1.x * __uint_as_float(uA.z << 16)
                 + q1.y * __uint_as_float(uA.z & 0xffff0000u)
                 + q1.z * __uint_as_float(uA.w << 16)
                 + q1.w * __uint_as_float(uA.w & 0xffff0000u);
        float dB = q0.x * __uint_as_float(uB.x << 16)
                 + q0.y * __uint_as_float(uB.x & 0xffff0000u)
                 + q0.z * __uint_as_float(uB.y << 16)
                 + q0.w * __uint_as_float(uB.y & 0xffff0000u)
                 + q1.x * __uint_as_float(uB.z << 16)
                 + q1.y * __uint_as_float(uB.z & 0xffff0000u)
                 + q1.z * __uint_as_float(uB.w << 16)
                 + q1.w * __uint_as_float(uB.w & 0xffff0000u);
#pragma unroll
        for (int m = 8; m >= 1; m >>= 1) {
            dA += __shfl_xor(dA, m);
            dB += __shfl_xor(dB, m);
        }
        const float enA = dA * inv_scale * __uint_as_float(rA.y);
        const float enB = dB * inv_scale * __uint_as_float(rB.y);
        if (vA) {
            lmax = fmaxf(lmax, enA);
            if (sl == 0) ((float*)erec)[2 * eA + 1] = enA;
        }
        if (vB) {
            lmax = fmaxf(lmax, enB);
            if (sl == 0) ((float*)erec)[2 * eB + 1] = enB;
        }
    }
#pragma unroll
    for (int m = 32; m >= 1; m >>= 1) lmax = fmaxf(lmax, __shfl_xor(lmax, m));
    __shared__ float sm[4];
    if (lane == 0) sm[threadIdx.x >> 6] = lmax;
    __syncthreads();
    if (threadIdx.x == 0)
        blockmax[blockIdx.x] = fmaxf(fmaxf(sm[0], sm[1]), fmaxf(sm[2], sm[3]));
}

__global__ __launch_bounds__(256) void reduce_max_kernel(
    const float* __restrict__ bm, int n, float* __restrict__ gmax)
{
    float m = -3.4e38f;
    for (int i = threadIdx.x; i < n; i += 256) m = fmaxf(m, bm[i]);
#pragma unroll
    for (int s = 32; s >= 1; s >>= 1) m = fmaxf(m, __shfl_xor(m, s));
    __shared__ float sm[4];
    if ((threadIdx.x & 63) == 0) sm[threadIdx.x >> 6] = m;
    __syncthreads();
    if (threadIdx.x == 0) *gmax = fmaxf(fmaxf(sm[0], sm[1]), fmaxf(sm[2], sm[3]));
}

// ---- Phase 4: erec.y = exp(erec.y - max); linear coalesced RMW ----
__global__ __launch_bounds__(256) void expsum_kernel(
    uint2* __restrict__ erec, const float* __restrict__ gmax,
    float* __restrict__ blocksum)
{
    const float m = *gmax;
    const int e = blockIdx.x * 256 + threadIdx.x;
    float p = 0.f;
    if (e < E_EDGES) {
        const uint2 r = erec[e];
        p = __expf(__uint_as_float(r.y) - m);
        erec[e] = make_uint2(r.x, __float_as_uint(p));
    }
#pragma unroll
    for (int s = 32; s >= 1; s >>= 1) p += __shfl_xor(p, s);
    __shared__ float sm[4];
    if ((threadIdx.x & 63) == 0) sm[threadIdx.x >> 6] = p;
    __syncthreads();
    if (threadIdx.x == 0) blocksum[blockIdx.x] = sm[0] + sm[1] + sm[2] + sm[3];
}

__global__ __launch_bounds__(256) void reduce_sum_kernel(
    const float* __restrict__ bs, int n, float* __restrict__ gsum)
{
    float v = 0.f;
    for (int i = threadIdx.x; i < n; i += 256) v += bs[i];
#pragma unroll
    for (int s = 32; s >= 1; s >>= 1) v += __shfl_xor(v, s);
    __shared__ float sm[4];
    if ((threadIdx.x & 63) == 0) sm[threadIdx.x >> 6] = v;
    __syncthreads();
    if (threadIdx.x == 0) *gsum = sm[0] + sm[1] + sm[2] + sm[3];
}

// ---- Phase 5: out[row] = sum_j V[col_j] * p_j / gsum; 8 edges in flight ----
__global__ __launch_bounds__(256) void accum_kernel(
    const unsigned short* __restrict__ Vb,
    const int* __restrict__ offs, const int* __restrict__ counts,
    const uint2* __restrict__ erec, const float* __restrict__ gsum,
    float* __restrict__ out)
{
    const int row  = (blockIdx.x * 256 + threadIdx.x) >> 6;
    const int lane = threadIdx.x & 63;
    const int eg   = lane >> 4;     // edge group 0..3
    const int sl   = lane & 15;     // sub-lane: dims sl*8..sl*8+7
    const float inv = 1.0f / *gsum;
    const int start = offs[row], len = counts[row];
    const uint4* vb128 = (const uint4*)Vb;   // one row = 16 uint4
    float aA[8] = {0.f, 0.f, 0.f, 0.f, 0.f, 0.f, 0.f, 0.f};
    float aB[8] = {0.f, 0.f, 0.f, 0.f, 0.f, 0.f, 0.f, 0.f};
    for (int j0 = 0; j0 < len; j0 += 8) {
        const int  jA = j0 + eg,      jB = j0 + 4 + eg;
        const bool vA = jA < len,     vB = jB < len;
        const int  eA = start + (vA ? jA : 0);
        const int  eB = start + (vB ? jB : 0);
        const uint2 rA = erec[eA];
        const uint2 rB = erec[eB];
        const float wA = vA ? __uint_as_float(rA.y) * inv : 0.f;
        const float wB = vB ? __uint_as_float(rB.y) * inv : 0.f;
        const uint4 uA = vb128[(size_t)rA.x * 16 + sl];
        const uint4 uB = vb128[(size_t)rB.x * 16 + sl];
        aA[0] += __uint_as_float(uA.x << 16) * wA;
        aA[1] += __uint_as_float(uA.x & 0xffff0000u) * wA;
        aA[2] += __uint_as_float(uA.y << 16) * wA;
        aA[3] += __uint_as_float(uA.y & 0xffff0000u) * wA;
        aA[4] += __uint_as_float(uA.z << 16) * wA;
        aA[5] += __uint_as_float(uA.z & 0xffff0000u) * wA;
        aA[6] += __uint_as_float(uA.w << 16) * wA;
        aA[7] += __uint_as_float(uA.w & 0xffff0000u) * wA;
        aB[0] += __uint_as_float(uB.x << 16) * wB;
        aB[1] += __uint_as_float(uB.x & 0xffff0000u) * wB;
        aB[2] += __uint_as_float(uB.y << 16) * wB;
        aB[3] += __uint_as_float(uB.y & 0xffff0000u) * wB;
        aB[4] += __uint_as_float(uB.z << 16) * wB;
        aB[5] += __uint_as_float(uB.z & 0xffff0000u) * wB;
        aB[6] += __uint_as_float(uB.w << 16) * wB;
        aB[7] += __uint_as_float(uB.w & 0xffff0000u) * wB;
    }
    float a[8];
#pragma unroll
    for (int i = 0; i < 8; ++i) {
        a[i] = aA[i] + aB[i];
        a[i] += __shfl_xor(a[i], 16);
        a[i] += __shfl_xor(a[i], 32);
    }
    if (eg == 0) {
        float* o = out + (size_t)row * HDIM + sl * 8;
        *(float4*)o       = make_float4(a[0], a[1], a[2], a[3]);
        *(float4*)(o + 4) = make_float4(a[4], a[5], a[6], a[7]);
    }
}

extern "C" void kernel_launch(void* const* d_in, const int* in_sizes, int n_in,
                              void* d_out, int out_size, void* d_ws, size_t ws_size,
                              hipStream_t stream)
{
    const float* x  = (const float*)d_in[0];
    const int*   ei = (const int*)d_in[1];
    const float* ew = (const float*)d_in[2];
    const float* Wq = (const float*)d_in[3];
    const float* bq = (const float*)d_in[4];
    const float* Wk = (const float*)d_in[5];
    const float* bk = (const float*)d_in[6];
    const float* Wv = (const float*)d_in[7];
    const float* bv = (const float*)d_in[8];
    float* out = (float*)d_out;

    float* ws = (float*)d_ws;
    float* Q       = ws;                                  // N*H fp32
    unsigned short* Kb = (unsigned short*)(Q + (size_t)N_NODES * HDIM);  // N*H bf16
    unsigned short* Vb = Kb + (size_t)N_NODES * HDIM;     // N*H bf16
    int*   counts  = (int*)(Vb + (size_t)N_NODES * HDIM); // N
    int*   offs    = counts + N_NODES;                    // N
    int*   cursor  = offs + N_NODES;                      // N
    int*   aux     = cursor + N_NODES;                    // SCAN_BLOCKS (256 slots)
    uint2* erec    = (uint2*)(aux + 256);                 // E records (col, ew/en/p)
    float* blockmax= (float*)(erec + E_EDGES);            // ROW_BLOCKS
    float* blocksum= blockmax + ROW_BLOCKS;               // EDGE_BLOCKS
    float* gmax    = blocksum + EDGE_BLOCKS;              // 1
    float* gsum    = gmax + 1;                            // 1

    hipMemsetAsync(counts, 0, N_NODES * sizeof(int), stream);

    qkv_mfma_kernel<<<dim3(QKV_BLOCKS, 3), 256, 0, stream>>>(
        x, Wq, bq, Wk, bk, Wv, bv, Q, Kb, Vb);
    hist_kernel<<<EDGE_BLOCKS, 256, 0, stream>>>(ei, counts);
    scan_partial_kernel<<<SCAN_BLOCKS, 256, 0, stream>>>(counts, offs, aux);
    scan_aux_kernel<<<1, 256, 0, stream>>>(aux);
    scan_add_kernel<<<SCAN_BLOCKS, 256, 0, stream>>>(offs, aux, cursor);
    bin_kernel<<<EDGE_BLOCKS, 256, 0, stream>>>(ei, ew, cursor, erec);
    energy_kernel<<<ROW_BLOCKS, 256, 0, stream>>>(Q, Kb, offs, counts, erec, blockmax);
    reduce_max_kernel<<<1, 256, 0, stream>>>(blockmax, ROW_BLOCKS, gmax);
    expsum_kernel<<<EDGE_BLOCKS, 256, 0, stream>>>(erec, gmax, blocksum);
    reduce_sum_kernel<<<1, 256, 0, stream>>>(blocksum, EDGE_BLOCKS, gsum);
    accum_kernel<<<ROW_BLOCKS, 256, 0, stream>>>(Vb, offs, counts, erec, gsum, out);
}